// Round 10
// baseline (1807.644 us; speedup 1.0000x reference)
//
#include <hip/hip_runtime.h>

typedef __attribute__((ext_vector_type(8))) short bf16x8;
typedef __attribute__((ext_vector_type(4))) float f32x4;

__device__ __forceinline__ unsigned short f2bf(float x) {
    unsigned u = __float_as_uint(x);
    u += 0x7FFFu + ((u >> 16) & 1u);
    return (unsigned short)(u >> 16);
}
__device__ __forceinline__ float sigm(float x) { return 1.0f / (1.0f + __expf(-x)); }
__device__ __forceinline__ float ftanh(float x) {
    float e = __expf(2.f * x);
    return 1.f - 2.f / (e + 1.f);
}

// async global->LDS, 16B/lane, wave-uniform LDS base + lane*16
__device__ __forceinline__ void gld16(const unsigned short* g, unsigned short* l) {
    __builtin_amdgcn_global_load_lds((const __attribute__((address_space(1))) void*)g,
                                     (__attribute__((address_space(3))) void*)l, 16, 0, 0);
}

// ---- flag primitives ----
// Raw (no sc1) atomic executes at the local XCD L2 and updates the L2 line;
// sc0 (GLC) load reads that same L2 line -> coherent intra-XCD, ~400cy RT.
// sc1 atomics execute at MALL; sc0sc1 loads read MALL -> cross-XCD, ~1100cy.
__device__ __forceinline__ void aaddL2(unsigned* p) {
    unsigned one = 1;
    asm volatile("global_atomic_add %0, %1, off" :: "v"(p), "v"(one) : "memory");
}
__device__ __forceinline__ void aaddMALL(unsigned* p) {
    unsigned one = 1;
    asm volatile("global_atomic_add %0, %1, off sc1" :: "v"(p), "v"(one) : "memory");
}
__device__ __forceinline__ unsigned ld_l2(const unsigned* p) {
    unsigned v;
    asm volatile("global_load_dword %0, %1, off sc0\n\ts_waitcnt vmcnt(0)"
                 : "=v"(v) : "v"(p) : "memory");
    return v;
}
__device__ __forceinline__ unsigned ld_mall(const unsigned* p) {
    unsigned v;
    asm volatile("global_load_dword %0, %1, off sc0 sc1\n\ts_waitcnt vmcnt(0)"
                 : "=v"(v) : "v"(p) : "memory");
    return v;
}
__device__ __forceinline__ void st_wt16(unsigned short* p, unsigned v) {  // bf16 write-through
    asm volatile("global_store_short %0, %1, off sc0 sc1" :: "v"(p), "v"(v) : "memory");
}

// DPP quad-lane exchanges (1-cycle VALU)
__device__ __forceinline__ float dppx1(float x) {
    return __int_as_float(__builtin_amdgcn_mov_dpp(__float_as_int(x), 0xB1, 0xF, 0xF, true));
}
__device__ __forceinline__ float dppx2(float x) {
    return __int_as_float(__builtin_amdgcn_mov_dpp(__float_as_int(x), 0x4E, 0xF, 0xF, true));
}

// ---------------- packing kernels (round-6-verified) ----------------
// Frag-order layout: slot(R,kc,lane): byte = ((R*16+kc)*64+lane)*16;
// elem e -> k = kc*32+(lane>>4)*8+e  == mfma_16x16x32 A/B fragment order.
__global__ __launch_bounds__(256) void k_conv_x(const float* __restrict__ x,
                                                unsigned short* __restrict__ Xp) {
    int i = blockIdx.x * 256 + threadIdx.x;
    int rb = i >> 10, kc = (i >> 6) & 15, ln = i & 63;
    int row = (rb << 4) + (ln & 15);
    int k   = (kc << 5) + ((ln >> 4) << 3);
    const float* s = x + (size_t)row * 512 + k;
    float4 v0 = *(const float4*)s, v1 = *(const float4*)(s + 4);
    unsigned short o[8] = {f2bf(v0.x), f2bf(v0.y), f2bf(v0.z), f2bf(v0.w),
                           f2bf(v1.x), f2bf(v1.y), f2bf(v1.z), f2bf(v1.w)};
    *(bf16x8*)(Xp + (size_t)i * 8) = *(bf16x8*)o;
}

__global__ __launch_bounds__(256) void k_conv_w(const float* __restrict__ Wih,
                                                const float* __restrict__ Whh,
                                                unsigned short* __restrict__ Wp) {
    int i = blockIdx.x * 256 + threadIdx.x;
    int wrb = i >> 11, kc = (i >> 6) & 31, ln = i & 63;
    int j = (wrb << 4) + (ln & 15);
    int k = (kc << 5) + ((ln >> 4) << 3);
    int srow = (j & 3) * 512 + (j >> 2);              // torch row g*512+hc
    const float* s = (k < 512) ? (Wih + (size_t)srow * 512 + k)
                               : (Whh + (size_t)srow * 512 + (k - 512));
    float4 v0 = *(const float4*)s, v1 = *(const float4*)(s + 4);
    unsigned short o[8] = {f2bf(v0.x), f2bf(v0.y), f2bf(v0.z), f2bf(v0.w),
                           f2bf(v1.x), f2bf(v1.y), f2bf(v1.z), f2bf(v1.w)};
    *(bf16x8*)(Wp + (size_t)i * 8) = *(bf16x8*)o;
}

struct DP {
    const unsigned short* Xp;
    unsigned short *Hp0, *Hp1, *Hp2;       // recurrence h: plain stores, intra-XCD L2
    unsigned short *Xq1, *Xq2;             // cross-layer x copies: sc1 write-through
    const unsigned short *Wp0, *Wp1, *Wp2;
    const float *bi0, *bh0, *bi1, *bh1, *bi2, *bh2;
    float* Out;
    unsigned int* flags;
};

__device__ __forceinline__ void quadT(f32x4 a, int sq, float& G0, float& G1, float& G2, float& G3) {
    float a0 = a[0], a1 = a[1], a2 = a[2], a3 = a[3];
    float p1 = (sq & 1) ? a0 : a1; float g1_ = dppx1(p1);
    float p2 = (sq & 1) ? a2 : a3; float g2_ = dppx1(p2);
    float m0 = (sq & 1) ? g1_ : a0, m1 = (sq & 1) ? a1 : g1_;
    float m2 = (sq & 1) ? g2_ : a2, m3 = (sq & 1) ? a3 : g2_;
    float q1 = (sq & 2) ? m0 : m2; float h1_ = dppx2(q1);
    float q2 = (sq & 2) ? m1 : m3; float h2_ = dppx2(q2);
    G0 = (sq & 2) ? h1_ : m0; G1 = (sq & 2) ? h2_ : m1;
    G2 = (sq & 2) ? m2 : h1_; G3 = (sq & 2) ? m3 : h2_;
}

#define PIN8(A,B,C,D,E,F,G,H) \
    asm volatile("" : "+v"(A),"+v"(B),"+v"(C),"+v"(D),"+v"(E),"+v"(F),"+v"(G),"+v"(H))

// Persistent dilated-LSTM, grid 256, XCD-clustered (cid = bid&7 -> XCD,
// w = bid>>3; r8-verified: plain-store/plain-load h coherent in-cluster).
//   cid 0,1: L0 (32 rows), T=256, P=1 | cid 2,3: L1 (64 rows), T=128, P=2
//   cid 4-7: L2 (64 rows), T=64, P=2
// Flags (sum semantics, per-cluster single dword):
//   iflagS[cid]: raw-L2 atomic publish, sc0-load poll, >= 32*t  (own recurrence)
//   mflagS[cid]: MALL mirror (escalation only, 64-iter trigger)
//   cflagS[cid]: MALL atomics, published ONE STEP LATE (sc1 data provably
//     retired: in-order vmcnt + counted waits). L1 c needs both L0 sums >=
//     32*(2t+c+1); L2 c needs L1[c&1] >= 32*(2t+(c>>1)+1)  [round-6-verified].
// Publisher = wave3 lane0 (acks drain in its own B0, off the poll path);
// poller = wave0 lane0 (iflag) / wave1 (cflag).
__global__ __launch_bounds__(256, 1) void k_drnn(DP p) {
    const int tid = threadIdx.x, lane = tid & 63, wv = tid >> 6;
    const int l15 = lane & 15, lhi = lane >> 4, sq = l15 & 3;

    const int b = blockIdx.x;
    const int cid = b & 7, w = b >> 3;
    int l, c, T, P, N;
    if (cid < 2)      { l = 0; c = cid;     T = 256; P = 1; N = 64;  }
    else if (cid < 4) { l = 1; c = cid - 2; T = 128; P = 2; N = 128; }
    else              { l = 2; c = cid - 4; T = 64;  P = 2; N = 256; }

    const unsigned short* Xs = (l == 0) ? p.Xp  : (l == 1 ? p.Xq1 : p.Xq2);
    unsigned short*       Hd = (l == 0) ? p.Hp0 : (l == 1 ? p.Hp1 : p.Hp2);
    unsigned short*       Xw = (l == 0) ? p.Xq1 : (l == 1 ? p.Xq2 : nullptr);
    const unsigned short* Ws = (l == 0) ? p.Wp0 : (l == 1 ? p.Wp1 : p.Wp2);
    const float* bi = (l == 0) ? p.bi0 : (l == 1 ? p.bi1 : p.bi2);
    const float* bh = (l == 0) ? p.bh0 : (l == 1 ? p.bh1 : p.bh2);
    const int R0 = c * (P * 32);
    const int alias = (p.Xq1 == p.Hp0);    // ws-fallback: sc1-only h path

    __shared__ unsigned short At[65536];   // 128 KiB

    const unsigned short* wbase = Ws + ((size_t)(((w << 2) + wv) * 32) << 9) + lane * 8;
#define DECLW(n) bf16x8 w##n = *(const bf16x8*)(wbase + (n << 9));
    DECLW(0) DECLW(1) DECLW(2) DECLW(3) DECLW(4) DECLW(5) DECLW(6) DECLW(7)
    DECLW(8) DECLW(9) DECLW(10) DECLW(11) DECLW(12) DECLW(13) DECLW(14) DECLW(15)
    DECLW(16) DECLW(17) DECLW(18) DECLW(19) DECLW(20) DECLW(21) DECLW(22) DECLW(23)
    DECLW(24) DECLW(25) DECLW(26) DECLW(27) DECLW(28) DECLW(29) DECLW(30) DECLW(31)

    const int hcol = (w << 4) + (wv << 2) + (l15 >> 2);
    const float bs0 = bi[hcol]        + bh[hcol];
    const float bs1 = bi[512 + hcol]  + bh[512 + hcol];
    const float bs2 = bi[1024 + hcol] + bh[1024 + hcol];
    const float bs3 = bi[1536 + hcol] + bh[1536 + hcol];

    const int kch = hcol >> 5;
    const int lane16 = (((hcol & 31) >> 3) << 4) + ((lhi << 2) + sq);
    const int st_lt = lane16 * 8 + (hcol & 7);

    float cst0 = 0.f, cst1 = 0.f, cst2 = 0.f, cst3 = 0.f;
    unsigned int* iflagS = p.flags;                 // + cid*32 (128B lines)
    unsigned int* mflagS = p.flags + 256;
    unsigned int* cflagS = p.flags + 512;

#define KPn(na, nb) { \
    bf16x8 xa = *(const bf16x8*)(a0 + ((na) << 9)); \
    bf16x8 xb = *(const bf16x8*)(a1 + ((na) << 9)); \
    bf16x8 ya = *(const bf16x8*)(a0 + ((nb) << 9)); \
    bf16x8 yb = *(const bf16x8*)(a1 + ((nb) << 9)); \
    e0 = __builtin_amdgcn_mfma_f32_16x16x32_bf16(xa, w##na, e0, 0, 0, 0); \
    e1 = __builtin_amdgcn_mfma_f32_16x16x32_bf16(xb, w##na, e1, 0, 0, 0); \
    o0 = __builtin_amdgcn_mfma_f32_16x16x32_bf16(ya, w##nb, o0, 0, 0, 0); \
    o1 = __builtin_amdgcn_mfma_f32_16x16x32_bf16(yb, w##nb, o1, 0, 0, 0); }

#define PWC(RV, CSTV, HV) { \
    float G0, G1, G2, G3; quadT(RV, sq, G0, G1, G2, G3); \
    float cn = sigm(G1 + bs1) * CSTV + sigm(G0 + bs0) * ftanh(G2 + bs2); \
    HV = sigm(G3 + bs3) * ftanh(cn); CSTV = cn; }

#define DOPASS(PI, CA, CB, HA, HB) { \
    const unsigned short* a0 = At + (((PI) * 64) << 9) + lane * 8; \
    const unsigned short* a1 = a0 + (32 << 9); \
    f32x4 e0 = {0.f,0.f,0.f,0.f}, o0 = {0.f,0.f,0.f,0.f}; \
    f32x4 e1 = {0.f,0.f,0.f,0.f}, o1 = {0.f,0.f,0.f,0.f}; \
    KPn(0,1) KPn(2,3) KPn(4,5) KPn(6,7) KPn(8,9) KPn(10,11) KPn(12,13) KPn(14,15) \
    KPn(16,17) KPn(18,19) KPn(20,21) KPn(22,23) KPn(24,25) KPn(26,27) KPn(28,29) KPn(30,31) \
    f32x4 r0 = e0 + o0, r1 = e1 + o1; \
    PWC(r0, CA, HA) PWC(r1, CB, HB) }

    for (int t = 0; t < T; ++t) {
        PIN8(w0,w1,w2,w3,w4,w5,w6,w7);
        PIN8(w8,w9,w10,w11,w12,w13,w14,w15);
        PIN8(w16,w17,w18,w19,w20,w21,w22,w23);
        PIN8(w24,w25,w26,w27,w28,w29,w30,w31);

        const int RxB = (t * N + R0) >> 4;

        if (l == 0) {   // prefetch x (static input) before the dependency wait
            #pragma unroll
            for (int i = 0; i < 8; ++i) {
                int q = (wv << 3) + i, rb = q >> 4, kc = q & 15;
                gld16(Xs + ((size_t)((RxB + rb) * 16 + kc) << 9) + lane * 8,
                      &At[(rb * 32 + kc) << 9]);
            }
        }

        // ---- own-recurrence wait: wave0 lane0, L2-scope sum, MALL escalation
        if (wv == 0 && lane == 0 && t > 0) {
            const unsigned need = 32u * (unsigned)t;
            const unsigned* ip = iflagS + cid * 32;
            const unsigned* mp = mflagS + cid * 32;
            int n = 0;
            while (ld_l2(ip) < need) {
                if (++n > 64) {                    // escalate: MALL mirror
                    int m = 0;
                    while (ld_mall(mp) < need) { if (++m > (1 << 22)) break; }
                    break;
                }
            }
        }
        // ---- cross-layer wait: wave1, MALL sums (delayed-visibility semantics)
        if (l == 1 && wv == 1 && lane < 2) {
            const unsigned* cp = cflagS + lane * 32;            // L0 c0, c1
            const unsigned need = 32u * (unsigned)(2 * t + c + 1);
            int n = 0;
            while (!__all(ld_mall(cp) >= need)) { if (++n > (1 << 22)) break; }
        }
        if (l == 2 && wv == 1 && lane == 0) {
            const unsigned* cp = cflagS + (2 + (c & 1)) * 32;   // L1 cluster c&1
            const unsigned need = 32u * (unsigned)(2 * t + (c >> 1) + 1);
            int n = 0;
            while (ld_mall(cp) < need) { if (++n > (1 << 22)) break; }
        }
        __syncthreads();                              // B0

        float hv0, hv1, hv2 = 0.f, hv3 = 0.f;
        if (l == 0) {
            if (t > 0) {
                const int RhB = ((t - 1) * N + R0) >> 4;
                #pragma unroll
                for (int i = 0; i < 8; ++i) {
                    int q = (wv << 3) + i, rb = q >> 4, kc = q & 15;
                    gld16(Hd + ((size_t)((RhB + rb) * 16 + kc) << 9) + lane * 8,
                          &At[(rb * 32 + 16 + kc) << 9]);
                }
            } else {
                #pragma unroll
                for (int rb = 0; rb < 2; ++rb)
                    #pragma unroll
                    for (int it = 0; it < 4; ++it)
                        *(float4*)&At[((rb * 32 + 16) << 9) + (it * 256 + tid) * 8] =
                            (float4){0.f, 0.f, 0.f, 0.f};
            }
            __builtin_amdgcn_sched_barrier(0);

            const unsigned short* a0 = At + lane * 8;
            const unsigned short* a1 = a0 + (32 << 9);
            f32x4 e0 = {0.f,0.f,0.f,0.f}, o0 = {0.f,0.f,0.f,0.f};
            f32x4 e1 = {0.f,0.f,0.f,0.f}, o1 = {0.f,0.f,0.f,0.f};
            KPn(0,1) KPn(2,3) KPn(4,5) KPn(6,7)
            KPn(8,9) KPn(10,11) KPn(12,13) KPn(14,15)
            __syncthreads();                          // B1 (h staged)
            KPn(16,17) KPn(18,19) KPn(20,21) KPn(22,23)
            KPn(24,25) KPn(26,27) KPn(28,29) KPn(30,31)
            f32x4 r0 = e0 + o0, r1 = e1 + o1;
            PWC(r0, cst0, hv0) PWC(r1, cst1, hv1)
        } else {
            #pragma unroll
            for (int i = 0; i < 16; ++i) {
                int q = (wv << 4) + i, rb = q >> 4, kc = q & 15;
                gld16(Xs + ((size_t)((RxB + rb) * 16 + kc) << 9) + lane * 8,
                      &At[(rb * 32 + kc) << 9]);
            }
            if (t > 0) {
                const int RhB = ((t - 1) * N + R0) >> 4;
                #pragma unroll
                for (int i = 0; i < 16; ++i) {
                    int q = (wv << 4) + i, rb = q >> 4, kc = q & 15;
                    gld16(Hd + ((size_t)((RhB + rb) * 16 + kc) << 9) + lane * 8,
                          &At[(rb * 32 + 16 + kc) << 9]);
                }
            } else {
                #pragma unroll
                for (int rb = 0; rb < 4; ++rb)
                    #pragma unroll
                    for (int it = 0; it < 4; ++it)
                        *(float4*)&At[((rb * 32 + 16) << 9) + (it * 256 + tid) * 8] =
                            (float4){0.f, 0.f, 0.f, 0.f};
            }
            __syncthreads();                          // B1
            DOPASS(0, cst0, cst1, hv0, hv1)
            DOPASS(1, cst2, cst3, hv2, hv3)
        }

        // ---- release: plain h first, sc1 Xq second, wait plain only
        const unsigned short hb0 = f2bf(hv0), hb1 = f2bf(hv1);
        const unsigned short hb2 = f2bf(hv2), hb3 = f2bf(hv3);
        const size_t i0 = ((size_t)((RxB + 0) * 16 + kch) << 9) + st_lt;
        const size_t i1 = ((size_t)((RxB + 1) * 16 + kch) << 9) + st_lt;
        const size_t i2 = ((size_t)((RxB + 2) * 16 + kch) << 9) + st_lt;
        const size_t i3 = ((size_t)((RxB + 3) * 16 + kch) << 9) + st_lt;
        if (!alias || l == 2) {
            Hd[i0] = hb0; Hd[i1] = hb1;
            if (P == 2) { Hd[i2] = hb2; Hd[i3] = hb3; }
        }
        if (l == 2) {
            p.Out[((size_t)(((RxB + 0) << 4) + (lhi << 2) + sq)) * 512 + hcol] = hv0;
            p.Out[((size_t)(((RxB + 1) << 4) + (lhi << 2) + sq)) * 512 + hcol] = hv1;
            p.Out[((size_t)(((RxB + 2) << 4) + (lhi << 2) + sq)) * 512 + hcol] = hv2;
            p.Out[((size_t)(((RxB + 3) << 4) + (lhi << 2) + sq)) * 512 + hcol] = hv3;
        }
        asm volatile("" ::: "memory");
        __builtin_amdgcn_sched_barrier(0);
        if (l == 0) { st_wt16(Xw + i0, hb0); st_wt16(Xw + i1, hb1); }
        else if (l == 1) { st_wt16(Xw + i0, hb0); st_wt16(Xw + i1, hb1);
                           st_wt16(Xw + i2, hb2); st_wt16(Xw + i3, hb3); }
        __builtin_amdgcn_sched_barrier(0);
        if (alias && l < 2)  asm volatile("s_waitcnt vmcnt(0)" ::: "memory");
        else if (l == 0)     asm volatile("s_waitcnt vmcnt(2)" ::: "memory");
        else                 asm volatile("s_waitcnt vmcnt(4)" ::: "memory");
        __builtin_amdgcn_sched_barrier(0);
        __builtin_amdgcn_s_barrier();                 // B2 (raw, no vmcnt(0) drain)
        __builtin_amdgcn_sched_barrier(0);
        // publisher = wave3 lane0: acks drain in ITS next B0, off the poll path
        if (tid == 192) {
            aaddL2(iflagS + cid * 32);
            aaddMALL(mflagS + cid * 32);
            if (l < 2 && t > 0) aaddMALL(cflagS + cid * 32);   // steps <= t-1 visible
        }
    }

    asm volatile("s_waitcnt vmcnt(0)" ::: "memory");
    __builtin_amdgcn_s_barrier();
    if (tid == 192 && l < 2) aaddMALL(cflagS + cid * 32);       // all T visible
}

extern "C" void kernel_launch(void* const* d_in, const int* in_sizes, int n_in,
                              void* d_out, int out_size, void* d_ws, size_t ws_size,
                              hipStream_t stream)
{
    const float* x = (const float*)d_in[0];
    const float* Wih[3] = {(const float*)d_in[1], (const float*)d_in[5], (const float*)d_in[9]};
    const float* Whh[3] = {(const float*)d_in[2], (const float*)d_in[6], (const float*)d_in[10]};
    const float* bih[3] = {(const float*)d_in[3], (const float*)d_in[7], (const float*)d_in[11]};
    const float* bhh[3] = {(const float*)d_in[4], (const float*)d_in[8], (const float*)d_in[12]};

    char* wp = (char*)d_ws;
    const size_t SZ_A = (size_t)16384 * 512;
    unsigned int* flags = (unsigned int*)wp; wp += 4096;
    unsigned short* Xp  = (unsigned short*)wp; wp += SZ_A * 2;
    unsigned short* Hp0 = (unsigned short*)wp; wp += SZ_A * 2;
    unsigned short* Hp1 = (unsigned short*)wp; wp += SZ_A * 2;
    unsigned short* Hp2 = (unsigned short*)wp; wp += SZ_A * 2;
    unsigned short* Wp[3];
    for (int l = 0; l < 3; ++l) { Wp[l] = (unsigned short*)wp; wp += (size_t)2048 * 1024 * 2; }
    unsigned short* Xq1 = (unsigned short*)wp; wp += SZ_A * 2;
    unsigned short* Xq2 = (unsigned short*)wp; wp += SZ_A * 2;
    // ws-fallback (r8 evidence says it doesn't fire): alias -> sc1-only h path
    const size_t need = (size_t)(wp - (char*)d_ws);
    if (ws_size < need) { Xq1 = Hp0; Xq2 = Hp1; }

    hipMemsetAsync(flags, 0, 4096, stream);
    k_conv_x<<<dim3(4096), dim3(256), 0, stream>>>(x, Xp);
    for (int l = 0; l < 3; ++l)
        k_conv_w<<<dim3(1024), dim3(256), 0, stream>>>(Wih[l], Whh[l], Wp[l]);

    DP dp;
    dp.Xp = Xp; dp.Hp0 = Hp0; dp.Hp1 = Hp1; dp.Hp2 = Hp2;
    dp.Xq1 = Xq1; dp.Xq2 = Xq2;
    dp.Wp0 = Wp[0]; dp.Wp1 = Wp[1]; dp.Wp2 = Wp[2];
    dp.bi0 = bih[0]; dp.bh0 = bhh[0];
    dp.bi1 = bih[1]; dp.bh1 = bhh[1];
    dp.bi2 = bih[2]; dp.bh2 = bhh[2];
    dp.Out = (float*)d_out; dp.flags = flags;

    k_drnn<<<dim3(256), dim3(256), 0, stream>>>(dp);
}

// Round 12
// 1598.923 us; speedup vs baseline: 1.1305x; 1.1305x over previous
//
#include <hip/hip_runtime.h>

typedef __attribute__((ext_vector_type(8))) short bf16x8;
typedef __attribute__((ext_vector_type(4))) float f32x4;

__device__ __forceinline__ unsigned short f2bf(float x) {
    unsigned u = __float_as_uint(x);
    u += 0x7FFFu + ((u >> 16) & 1u);
    return (unsigned short)(u >> 16);
}
__device__ __forceinline__ float sigm(float x) { return 1.0f / (1.0f + __expf(-x)); }
__device__ __forceinline__ float ftanh(float x) {
    float e = __expf(2.f * x);
    return 1.f - 2.f / (e + 1.f);
}

// async global->LDS, 16B/lane, wave-uniform LDS base + lane*16
__device__ __forceinline__ void gld16(const unsigned short* g, unsigned short* l) {
    __builtin_amdgcn_global_load_lds((const __attribute__((address_space(1))) void*)g,
                                     (__attribute__((address_space(3))) void*)l, 16, 0, 0);
}

// ---- flag primitives ----
__device__ __forceinline__ void st_plain32(unsigned* p, unsigned v) {  // L1 write-through -> XCD L2
    asm volatile("global_store_dword %0, %1, off" :: "v"(p), "v"(v) : "memory");
}
__device__ __forceinline__ void st_wt32(unsigned* p, unsigned v) {     // -> MALL
    asm volatile("global_store_dword %0, %1, off sc0 sc1" :: "v"(p), "v"(v) : "memory");
}
__device__ __forceinline__ void aaddMALL(unsigned* p) {
    unsigned one = 1;
    asm volatile("global_atomic_add %0, %1, off sc1" :: "v"(p), "v"(one) : "memory");
}
__device__ __forceinline__ unsigned ld_l2(const unsigned* p) {         // bypass L1, read XCD L2
    unsigned v;
    asm volatile("global_load_dword %0, %1, off sc0\n\ts_waitcnt vmcnt(0)"
                 : "=v"(v) : "v"(p) : "memory");
    return v;
}
__device__ __forceinline__ unsigned ld_mall(const unsigned* p) {       // read MALL
    unsigned v;
    asm volatile("global_load_dword %0, %1, off sc0 sc1\n\ts_waitcnt vmcnt(0)"
                 : "=v"(v) : "v"(p) : "memory");
    return v;
}
__device__ __forceinline__ void st_wt16(unsigned short* p, unsigned v) {
    asm volatile("global_store_short %0, %1, off sc0 sc1" :: "v"(p), "v"(v) : "memory");
}

// DPP quad-lane exchanges (1-cycle VALU)
__device__ __forceinline__ float dppx1(float x) {
    return __int_as_float(__builtin_amdgcn_mov_dpp(__float_as_int(x), 0xB1, 0xF, 0xF, true));
}
__device__ __forceinline__ float dppx2(float x) {
    return __int_as_float(__builtin_amdgcn_mov_dpp(__float_as_int(x), 0x4E, 0xF, 0xF, true));
}

// ---------------- packing kernels (round-6-verified) ----------------
__global__ __launch_bounds__(256) void k_conv_x(const float* __restrict__ x,
                                                unsigned short* __restrict__ Xp) {
    int i = blockIdx.x * 256 + threadIdx.x;
    int rb = i >> 10, kc = (i >> 6) & 15, ln = i & 63;
    int row = (rb << 4) + (ln & 15);
    int k   = (kc << 5) + ((ln >> 4) << 3);
    const float* s = x + (size_t)row * 512 + k;
    float4 v0 = *(const float4*)s, v1 = *(const float4*)(s + 4);
    unsigned short o[8] = {f2bf(v0.x), f2bf(v0.y), f2bf(v0.z), f2bf(v0.w),
                           f2bf(v1.x), f2bf(v1.y), f2bf(v1.z), f2bf(v1.w)};
    *(bf16x8*)(Xp + (size_t)i * 8) = *(bf16x8*)o;
}

__global__ __launch_bounds__(256) void k_conv_w(const float* __restrict__ Wih,
                                                const float* __restrict__ Whh,
                                                unsigned short* __restrict__ Wp) {
    int i = blockIdx.x * 256 + threadIdx.x;
    int wrb = i >> 11, kc = (i >> 6) & 31, ln = i & 63;
    int j = (wrb << 4) + (ln & 15);
    int k = (kc << 5) + ((ln >> 4) << 3);
    int srow = (j & 3) * 512 + (j >> 2);              // torch row g*512+hc
    const float* s = (k < 512) ? (Wih + (size_t)srow * 512 + k)
                               : (Whh + (size_t)srow * 512 + (k - 512));
    float4 v0 = *(const float4*)s, v1 = *(const float4*)(s + 4);
    unsigned short o[8] = {f2bf(v0.x), f2bf(v0.y), f2bf(v0.z), f2bf(v0.w),
                           f2bf(v1.x), f2bf(v1.y), f2bf(v1.z), f2bf(v1.w)};
    *(bf16x8*)(Wp + (size_t)i * 8) = *(bf16x8*)o;
}

struct DP {
    const unsigned short* Xp;
    unsigned short *Hp0, *Hp1, *Hp2;
    unsigned short *Xq1, *Xq2;
    const unsigned short *Wp0, *Wp1, *Wp2;
    const float *bi0, *bh0, *bi1, *bh1, *bi2, *bh2;
    float* Out;
    unsigned int* flags;   // [0,256) iflagV, [256,512) mflagV, [512,768) cflagS
};

__device__ __forceinline__ void quadT(f32x4 a, int sq, float& G0, float& G1, float& G2, float& G3) {
    float a0 = a[0], a1 = a[1], a2 = a[2], a3 = a[3];
    float p1 = (sq & 1) ? a0 : a1; float g1_ = dppx1(p1);
    float p2 = (sq & 1) ? a2 : a3; float g2_ = dppx1(p2);
    float m0 = (sq & 1) ? g1_ : a0, m1 = (sq & 1) ? a1 : g1_;
    float m2 = (sq & 1) ? g2_ : a2, m3 = (sq & 1) ? a3 : g2_;
    float q1 = (sq & 2) ? m0 : m2; float h1_ = dppx2(q1);
    float q2 = (sq & 2) ? m1 : m3; float h2_ = dppx2(q2);
    G0 = (sq & 2) ? h1_ : m0; G1 = (sq & 2) ? h2_ : m1;
    G2 = (sq & 2) ? m2 : h1_; G3 = (sq & 2) ? m3 : h2_;
}

#define PIN8(A,B,C,D,E,F,G,H) \
    asm volatile("" : "+v"(A),"+v"(B),"+v"(C),"+v"(D),"+v"(E),"+v"(F),"+v"(G),"+v"(H))
#define SBAR()  __builtin_amdgcn_sched_barrier(0)
#define MEMBAR() asm volatile("" ::: "memory")
#define RAWBAR() do { MEMBAR(); SBAR(); __builtin_amdgcn_s_barrier(); SBAR(); MEMBAR(); } while (0)

// Persistent dilated-LSTM, grid 256, XCD-clustered (cid = bid&7, w = bid>>3;
// r8-PROVEN: plain-store h -> plain-load within cluster is coherent => same-XCD).
//   cid 0,1: L0 (32 rows), T=256, P=1 | cid 2,3: L1 (64 rows), T=128, P=2
//   cid 4-7: L2 (64 rows), T=64, P=2
// Wave roles (vmcnt retires IN ORDER, so publishers must not stage pre-B0):
//   w0: iflag poll + x-stage      w1: cflag poll + x-stage
//   w2: h-stage + cflag publish   w3: h-stage + iflag/mirror publish
// Barriers all RAW, each preceded by per-wave counted self-drains:
//   B0: wv<2 vmcnt(0)  (x staged; w2/3 publish-acks still flying - harmless)
//   B1: wv>=2 vmcnt(0) (h staged; pubs ~1000cy old = already retired) + lgkm(0)
//   B2: counted vmcnt (h plain-store acks only)
// iflag: plain store (XCD L2), sc0 poll EXACT-MATCH+slack (v-t<=1): legit skew
//   <=1; only realistic stale value is T (end-of-replay line) which is rejected
//   for all t<T-1; t==T-1 gates via MALL mirror. 4096-iter escalation.
// cflag: MALL atomic sums, one step delayed (r9-verified formulas).
__global__ __launch_bounds__(256, 1) void k_drnn(DP p) {
    const int tid = threadIdx.x, lane = tid & 63, wv = tid >> 6;
    const int l15 = lane & 15, lhi = lane >> 4, sq = l15 & 3;

    const int b = blockIdx.x;
    const int cid = b & 7, w = b >> 3;
    int l, c, T, P, N;
    if (cid < 2)      { l = 0; c = cid;     T = 256; P = 1; N = 64;  }
    else if (cid < 4) { l = 1; c = cid - 2; T = 128; P = 2; N = 128; }
    else              { l = 2; c = cid - 4; T = 64;  P = 2; N = 256; }

    const unsigned short* Xs = (l == 0) ? p.Xp  : (l == 1 ? p.Xq1 : p.Xq2);
    unsigned short*       Hd = (l == 0) ? p.Hp0 : (l == 1 ? p.Hp1 : p.Hp2);
    unsigned short*       Xw = (l == 0) ? p.Xq1 : (l == 1 ? p.Xq2 : nullptr);
    const unsigned short* Ws = (l == 0) ? p.Wp0 : (l == 1 ? p.Wp1 : p.Wp2);
    const float* bi = (l == 0) ? p.bi0 : (l == 1 ? p.bi1 : p.bi2);
    const float* bh = (l == 0) ? p.bh0 : (l == 1 ? p.bh1 : p.bh2);
    const int R0 = c * (P * 32);
    const int alias = (p.Xq1 == p.Hp0);

    __shared__ unsigned short At[65536];   // 128 KiB

    const unsigned short* wbase = Ws + ((size_t)(((w << 2) + wv) * 32) << 9) + lane * 8;
#define DECLW(n) bf16x8 w##n = *(const bf16x8*)(wbase + (n << 9));
    DECLW(0) DECLW(1) DECLW(2) DECLW(3) DECLW(4) DECLW(5) DECLW(6) DECLW(7)
    DECLW(8) DECLW(9) DECLW(10) DECLW(11) DECLW(12) DECLW(13) DECLW(14) DECLW(15)
    DECLW(16) DECLW(17) DECLW(18) DECLW(19) DECLW(20) DECLW(21) DECLW(22) DECLW(23)
    DECLW(24) DECLW(25) DECLW(26) DECLW(27) DECLW(28) DECLW(29) DECLW(30) DECLW(31)

    const int hcol = (w << 4) + (wv << 2) + (l15 >> 2);
    const float bs0 = bi[hcol]        + bh[hcol];
    const float bs1 = bi[512 + hcol]  + bh[512 + hcol];
    const float bs2 = bi[1024 + hcol] + bh[1024 + hcol];
    const float bs3 = bi[1536 + hcol] + bh[1536 + hcol];

    const int kch = hcol >> 5;
    const int lane16 = (((hcol & 31) >> 3) << 4) + ((lhi << 2) + sq);
    const int st_lt = lane16 * 8 + (hcol & 7);

    float cst0 = 0.f, cst1 = 0.f, cst2 = 0.f, cst3 = 0.f;
    unsigned int* iflagV = p.flags;
    unsigned int* mflagV = p.flags + 256;
    unsigned int* cflagS = p.flags + 512;
    int fastok = 1;

#define KPn(na, nb) { \
    bf16x8 xa = *(const bf16x8*)(a0 + ((na) << 9)); \
    bf16x8 xb = *(const bf16x8*)(a1 + ((na) << 9)); \
    bf16x8 ya = *(const bf16x8*)(a0 + ((nb) << 9)); \
    bf16x8 yb = *(const bf16x8*)(a1 + ((nb) << 9)); \
    e0 = __builtin_amdgcn_mfma_f32_16x16x32_bf16(xa, w##na, e0, 0, 0, 0); \
    e1 = __builtin_amdgcn_mfma_f32_16x16x32_bf16(xb, w##na, e1, 0, 0, 0); \
    o0 = __builtin_amdgcn_mfma_f32_16x16x32_bf16(ya, w##nb, o0, 0, 0, 0); \
    o1 = __builtin_amdgcn_mfma_f32_16x16x32_bf16(yb, w##nb, o1, 0, 0, 0); }

#define PWC(RV, CSTV, HV) { \
    float G0, G1, G2, G3; quadT(RV, sq, G0, G1, G2, G3); \
    float cn = sigm(G1 + bs1) * CSTV + sigm(G0 + bs0) * ftanh(G2 + bs2); \
    HV = sigm(G3 + bs3) * ftanh(cn); CSTV = cn; }

#define DOPASS(PI, CA, CB, HA, HB) { \
    const unsigned short* a0 = At + (((PI) * 64) << 9) + lane * 8; \
    const unsigned short* a1 = a0 + (32 << 9); \
    f32x4 e0 = {0.f,0.f,0.f,0.f}, o0 = {0.f,0.f,0.f,0.f}; \
    f32x4 e1 = {0.f,0.f,0.f,0.f}, o1 = {0.f,0.f,0.f,0.f}; \
    KPn(0,1) KPn(2,3) KPn(4,5) KPn(6,7) KPn(8,9) KPn(10,11) KPn(12,13) KPn(14,15) \
    KPn(16,17) KPn(18,19) KPn(20,21) KPn(22,23) KPn(24,25) KPn(26,27) KPn(28,29) KPn(30,31) \
    f32x4 r0 = e0 + o0, r1 = e1 + o1; \
    PWC(r0, CA, HA) PWC(r1, CB, HB) }

    for (int t = 0; t < T; ++t) {
        PIN8(w0,w1,w2,w3,w4,w5,w6,w7);
        PIN8(w8,w9,w10,w11,w12,w13,w14,w15);
        PIN8(w16,w17,w18,w19,w20,w21,w22,w23);
        PIN8(w24,w25,w26,w27,w28,w29,w30,w31);

        const int RxB = (t * N + R0) >> 4;

        // L0: waves 0/1 prefetch ALL x chunks (static input) before the polls
        if (l == 0 && wv < 2) {
            #pragma unroll
            for (int i = 0; i < 16; ++i) {
                int q = (wv << 4) + i, rb = q >> 4, kc = q & 15;
                gld16(Xs + ((size_t)((RxB + rb) * 16 + kc) << 9) + lane * 8,
                      &At[(rb * 32 + kc) << 9]);
            }
        }

        // ---- wave0: own-cluster iflag poll (exact-match + slack 1)
        if (wv == 0 && t > 0) {
            const unsigned need = (unsigned)t;
            const unsigned* ip = iflagV + cid * 32 + (lane & 31);
            const unsigned* mp = mflagV + cid * 32 + (lane & 31);
            if (t == T - 1 || !fastok) {            // authoritative MALL gate
                int n = 0;
                while (!__all(ld_mall(mp) >= need)) { if (++n > (1 << 22)) break; }
            } else {
                int n = 0;
                for (;;) {
                    unsigned v = ld_l2(ip);
                    if (__all((v - need) <= 1u)) break;
                    if (++n > 4096) {
                        fastok = 0;
                        int m = 0;
                        while (!__all(ld_mall(mp) >= need)) { if (++m > (1 << 22)) break; }
                        break;
                    }
                }
            }
        }
        // ---- wave1: cross-layer cflag poll (MALL sums, r9-verified)
        if (l == 1 && wv == 1 && lane < 2) {
            const unsigned* cp = cflagS + lane * 32;
            const unsigned need = 32u * (unsigned)(2 * t + c + 1);
            int n = 0;
            while (!__all(ld_mall(cp) >= need)) { if (++n > (1 << 22)) break; }
        }
        if (l == 2 && wv == 1 && lane == 0) {
            const unsigned* cp = cflagS + (2 + (c & 1)) * 32;
            const unsigned need = 32u * (unsigned)(2 * t + (c >> 1) + 1);
            int n = 0;
            while (ld_mall(cp) < need) { if (++n > (1 << 22)) break; }
        }
        if (wv < 2) asm volatile("s_waitcnt vmcnt(0)" ::: "memory");  // x staged (own)
        RAWBAR();                                                     // B0

        float hv0, hv1, hv2 = 0.f, hv3 = 0.f;
        if (l == 0) {
            if (t > 0) {
                if (wv >= 2) {                       // h-stage by publisher waves
                    const int RhB = ((t - 1) * N + R0) >> 4;
                    #pragma unroll
                    for (int i = 0; i < 16; ++i) {
                        int q = ((wv - 2) << 4) + i, rb = q >> 4, kc = q & 15;
                        gld16(Hd + ((size_t)((RhB + rb) * 16 + kc) << 9) + lane * 8,
                              &At[(rb * 32 + 16 + kc) << 9]);
                    }
                }
            } else {
                #pragma unroll
                for (int rb = 0; rb < 2; ++rb)
                    #pragma unroll
                    for (int it = 0; it < 4; ++it)
                        *(float4*)&At[((rb * 32 + 16) << 9) + (it * 256 + tid) * 8] =
                            (float4){0.f, 0.f, 0.f, 0.f};
            }
            SBAR();
            // x-half MFMAs run while h loads fly (x drained at B0 by all stagers)
            const unsigned short* a0 = At + lane * 8;
            const unsigned short* a1 = a0 + (32 << 9);
            f32x4 e0 = {0.f,0.f,0.f,0.f}, o0 = {0.f,0.f,0.f,0.f};
            f32x4 e1 = {0.f,0.f,0.f,0.f}, o1 = {0.f,0.f,0.f,0.f};
            KPn(0,1) KPn(2,3) KPn(4,5) KPn(6,7)
            KPn(8,9) KPn(10,11) KPn(12,13) KPn(14,15)
            if (wv >= 2) asm volatile("s_waitcnt vmcnt(0)" ::: "memory");  // h staged (own; pubs long-retired)
            asm volatile("s_waitcnt lgkmcnt(0)" ::: "memory");             // t==0 zero-fill
            RAWBAR();                                                      // B1
            KPn(16,17) KPn(18,19) KPn(20,21) KPn(22,23)
            KPn(24,25) KPn(26,27) KPn(28,29) KPn(30,31)
            f32x4 r0 = e0 + o0, r1 = e1 + o1;
            PWC(r0, cst0, hv0) PWC(r1, cst1, hv1)
        } else {
            if (wv < 2) {                            // x-stage (flag-gated)
                #pragma unroll
                for (int i = 0; i < 32; ++i) {
                    int q = (wv << 5) + i, rb = q >> 4, kc = q & 15;
                    gld16(Xs + ((size_t)((RxB + rb) * 16 + kc) << 9) + lane * 8,
                          &At[(rb * 32 + kc) << 9]);
                }
            }
            if (t > 0) {
                if (wv >= 2) {                       // h-stage
                    const int RhB = ((t - 1) * N + R0) >> 4;
                    #pragma unroll
                    for (int i = 0; i < 32; ++i) {
                        int q = ((wv - 2) << 5) + i, rb = q >> 4, kc = q & 15;
                        gld16(Hd + ((size_t)((RhB + rb) * 16 + kc) << 9) + lane * 8,
                              &At[(rb * 32 + 16 + kc) << 9]);
                    }
                }
            } else {
                #pragma unroll
                for (int rb = 0; rb < 4; ++rb)
                    #pragma unroll
                    for (int it = 0; it < 4; ++it)
                        *(float4*)&At[((rb * 32 + 16) << 9) + (it * 256 + tid) * 8] =
                            (float4){0.f, 0.f, 0.f, 0.f};
            }
            asm volatile("s_waitcnt vmcnt(0)" ::: "memory");   // own stage drained (pubs retired)
            asm volatile("s_waitcnt lgkmcnt(0)" ::: "memory");
            RAWBAR();                                           // B1
            DOPASS(0, cst0, cst1, hv0, hv1)
            DOPASS(1, cst2, cst3, hv2, hv3)
        }

        // ---- release: plain h, (Out), then sc1 Xq; counted wait = h acks only
        const unsigned short hb0 = f2bf(hv0), hb1 = f2bf(hv1);
        const unsigned short hb2 = f2bf(hv2), hb3 = f2bf(hv3);
        const size_t i0 = ((size_t)((RxB + 0) * 16 + kch) << 9) + st_lt;
        const size_t i1 = ((size_t)((RxB + 1) * 16 + kch) << 9) + st_lt;
        const size_t i2 = ((size_t)((RxB + 2) * 16 + kch) << 9) + st_lt;
        const size_t i3 = ((size_t)((RxB + 3) * 16 + kch) << 9) + st_lt;
        if (!alias || l == 2) {
            Hd[i0] = hb0; Hd[i1] = hb1;
            if (P == 2) { Hd[i2] = hb2; Hd[i3] = hb3; }
        }
        if (l == 2) {
            p.Out[((size_t)(((RxB + 0) << 4) + (lhi << 2) + sq)) * 512 + hcol] = hv0;
            p.Out[((size_t)(((RxB + 1) << 4) + (lhi << 2) + sq)) * 512 + hcol] = hv1;
            p.Out[((size_t)(((RxB + 2) << 4) + (lhi << 2) + sq)) * 512 + hcol] = hv2;
            p.Out[((size_t)(((RxB + 3) << 4) + (lhi << 2) + sq)) * 512 + hcol] = hv3;
        }
        MEMBAR(); SBAR();
        if (l == 0) { st_wt16(Xw + i0, hb0); st_wt16(Xw + i1, hb1); }
        else if (l == 1) { st_wt16(Xw + i0, hb0); st_wt16(Xw + i1, hb1);
                           st_wt16(Xw + i2, hb2); st_wt16(Xw + i3, hb3); }
        SBAR();
        if (alias && l < 2)  asm volatile("s_waitcnt vmcnt(0)" ::: "memory");
        else if (l == 0)     asm volatile("s_waitcnt vmcnt(2)" ::: "memory");  // 2h acked, 2 Xw fly
        else                 asm volatile("s_waitcnt vmcnt(4)" ::: "memory");  // 4h acked
        RAWBAR();                                           // B2
        // publishers: fire-and-forget; acks retire before their next B1 drain
        if (tid == 192) {
            st_plain32(iflagV + cid * 32 + w, (unsigned)(t + 1));   // XCD L2 fast path
            st_wt32(mflagV + cid * 32 + w, (unsigned)(t + 1));      // MALL mirror
        }
        if (tid == 128 && l < 2 && t > 0) aaddMALL(cflagS + cid * 32);  // steps <= t-1
    }

    asm volatile("s_waitcnt vmcnt(0)" ::: "memory");
    __builtin_amdgcn_s_barrier();
    if (tid == 128 && l < 2) aaddMALL(cflagS + cid * 32);           // all T visible
}

extern "C" void kernel_launch(void* const* d_in, const int* in_sizes, int n_in,
                              void* d_out, int out_size, void* d_ws, size_t ws_size,
                              hipStream_t stream)
{
    const float* x = (const float*)d_in[0];
    const float* Wih[3] = {(const float*)d_in[1], (const float*)d_in[5], (const float*)d_in[9]};
    const float* Whh[3] = {(const float*)d_in[2], (const float*)d_in[6], (const float*)d_in[10]};
    const float* bih[3] = {(const float*)d_in[3], (const float*)d_in[7], (const float*)d_in[11]};
    const float* bhh[3] = {(const float*)d_in[4], (const float*)d_in[8], (const float*)d_in[12]};

    char* wp = (char*)d_ws;
    const size_t SZ_A = (size_t)16384 * 512;
    unsigned int* flags = (unsigned int*)wp; wp += 4096;
    unsigned short* Xp  = (unsigned short*)wp; wp += SZ_A * 2;
    unsigned short* Hp0 = (unsigned short*)wp; wp += SZ_A * 2;
    unsigned short* Hp1 = (unsigned short*)wp; wp += SZ_A * 2;
    unsigned short* Hp2 = (unsigned short*)wp; wp += SZ_A * 2;
    unsigned short* Wp[3];
    for (int l = 0; l < 3; ++l) { Wp[l] = (unsigned short*)wp; wp += (size_t)2048 * 1024 * 2; }
    unsigned short* Xq1 = (unsigned short*)wp; wp += SZ_A * 2;
    unsigned short* Xq2 = (unsigned short*)wp; wp += SZ_A * 2;
    const size_t need = (size_t)(wp - (char*)d_ws);
    if (ws_size < need) { Xq1 = Hp0; Xq2 = Hp1; }   // fallback: sc1-only h path

    hipMemsetAsync(flags, 0, 4096, stream);
    k_conv_x<<<dim3(4096), dim3(256), 0, stream>>>(x, Xp);
    for (int l = 0; l < 3; ++l)
        k_conv_w<<<dim3(1024), dim3(256), 0, stream>>>(Wih[l], Whh[l], Wp[l]);

    DP dp;
    dp.Xp = Xp; dp.Hp0 = Hp0; dp.Hp1 = Hp1; dp.Hp2 = Hp2;
    dp.Xq1 = Xq1; dp.Xq2 = Xq2;
    dp.Wp0 = Wp[0]; dp.Wp1 = Wp[1]; dp.Wp2 = Wp[2];
    dp.bi0 = bih[0]; dp.bh0 = bhh[0];
    dp.bi1 = bih[1]; dp.bh1 = bhh[1];
    dp.bi2 = bih[2]; dp.bh2 = bhh[2];
    dp.Out = (float*)d_out; dp.flags = flags;

    k_drnn<<<dim3(256), dim3(256), 0, stream>>>(dp);
}

// Round 13
// 951.509 us; speedup vs baseline: 1.8998x; 1.6804x over previous
//
#include <hip/hip_runtime.h>

typedef __attribute__((ext_vector_type(8))) short bf16x8;
typedef __attribute__((ext_vector_type(4))) float f32x4;

__device__ __forceinline__ unsigned short f2bf(float x) {
    unsigned u = __float_as_uint(x);
    u += 0x7FFFu + ((u >> 16) & 1u);
    return (unsigned short)(u >> 16);
}
__device__ __forceinline__ float sigm(float x) { return 1.0f / (1.0f + __expf(-x)); }
__device__ __forceinline__ float ftanh(float x) {
    float e = __expf(2.f * x);
    return 1.f - 2.f / (e + 1.f);
}

// async global->LDS, 16B/lane, wave-uniform LDS base + lane*16
__device__ __forceinline__ void gld16(const unsigned short* g, unsigned short* l) {
    __builtin_amdgcn_global_load_lds((const __attribute__((address_space(1))) void*)g,
                                     (__attribute__((address_space(3))) void*)l, 16, 0, 0);
}

// ---- flag primitives ----
__device__ __forceinline__ void st_plain32(unsigned* p, unsigned v) {  // -> XCD L2 (write-through L1)
    asm volatile("global_store_dword %0, %1, off" :: "v"(p), "v"(v) : "memory");
}
__device__ __forceinline__ void st_wt32(unsigned* p, unsigned v) {     // -> MALL
    asm volatile("global_store_dword %0, %1, off sc0 sc1" :: "v"(p), "v"(v) : "memory");
}
__device__ __forceinline__ void aaddMALL(unsigned* p) {
    unsigned one = 1;
    asm volatile("global_atomic_add %0, %1, off sc1" :: "v"(p), "v"(one) : "memory");
}
__device__ __forceinline__ unsigned ld_mall(const unsigned* p) {       // read MALL
    unsigned v;
    asm volatile("global_load_dword %0, %1, off sc0 sc1\n\ts_waitcnt vmcnt(0)"
                 : "=v"(v) : "v"(p) : "memory");
    return v;
}
__device__ __forceinline__ void st_wt16(unsigned short* p, unsigned v) {
    asm volatile("global_store_short %0, %1, off sc0 sc1" :: "v"(p), "v"(v) : "memory");
}

// DPP quad-lane exchanges (1-cycle VALU)
__device__ __forceinline__ float dppx1(float x) {
    return __int_as_float(__builtin_amdgcn_mov_dpp(__float_as_int(x), 0xB1, 0xF, 0xF, true));
}
__device__ __forceinline__ float dppx2(float x) {
    return __int_as_float(__builtin_amdgcn_mov_dpp(__float_as_int(x), 0x4E, 0xF, 0xF, true));
}

// ---------------- packing kernels (round-6-verified) ----------------
__global__ __launch_bounds__(256) void k_conv_x(const float* __restrict__ x,
                                                unsigned short* __restrict__ Xp) {
    int i = blockIdx.x * 256 + threadIdx.x;
    int rb = i >> 10, kc = (i >> 6) & 15, ln = i & 63;
    int row = (rb << 4) + (ln & 15);
    int k   = (kc << 5) + ((ln >> 4) << 3);
    const float* s = x + (size_t)row * 512 + k;
    float4 v0 = *(const float4*)s, v1 = *(const float4*)(s + 4);
    unsigned short o[8] = {f2bf(v0.x), f2bf(v0.y), f2bf(v0.z), f2bf(v0.w),
                           f2bf(v1.x), f2bf(v1.y), f2bf(v1.z), f2bf(v1.w)};
    *(bf16x8*)(Xp + (size_t)i * 8) = *(bf16x8*)o;
}

__global__ __launch_bounds__(256) void k_conv_w(const float* __restrict__ Wih,
                                                const float* __restrict__ Whh,
                                                unsigned short* __restrict__ Wp) {
    int i = blockIdx.x * 256 + threadIdx.x;
    int wrb = i >> 11, kc = (i >> 6) & 31, ln = i & 63;
    int j = (wrb << 4) + (ln & 15);
    int k = (kc << 5) + ((ln >> 4) << 3);
    int srow = (j & 3) * 512 + (j >> 2);              // torch row g*512+hc
    const float* s = (k < 512) ? (Wih + (size_t)srow * 512 + k)
                               : (Whh + (size_t)srow * 512 + (k - 512));
    float4 v0 = *(const float4*)s, v1 = *(const float4*)(s + 4);
    unsigned short o[8] = {f2bf(v0.x), f2bf(v0.y), f2bf(v0.z), f2bf(v0.w),
                           f2bf(v1.x), f2bf(v1.y), f2bf(v1.z), f2bf(v1.w)};
    *(bf16x8*)(Wp + (size_t)i * 8) = *(bf16x8*)o;
}

struct DP {
    const unsigned short* Xp;
    unsigned short *Hp0, *Hp1, *Hp2;
    unsigned short *Xq1, *Xq2;
    const unsigned short *Wp0, *Wp1, *Wp2;
    const float *bi0, *bh0, *bi1, *bh1, *bi2, *bh2;
    float* Out;
    unsigned int* flags;   // [0,256) iflagV, [256,512) mflagV, [512,768) cflagS
};

__device__ __forceinline__ void quadT(f32x4 a, int sq, float& G0, float& G1, float& G2, float& G3) {
    float a0 = a[0], a1 = a[1], a2 = a[2], a3 = a[3];
    float p1 = (sq & 1) ? a0 : a1; float g1_ = dppx1(p1);
    float p2 = (sq & 1) ? a2 : a3; float g2_ = dppx1(p2);
    float m0 = (sq & 1) ? g1_ : a0, m1 = (sq & 1) ? a1 : g1_;
    float m2 = (sq & 1) ? g2_ : a2, m3 = (sq & 1) ? a3 : g2_;
    float q1 = (sq & 2) ? m0 : m2; float h1_ = dppx2(q1);
    float q2 = (sq & 2) ? m1 : m3; float h2_ = dppx2(q2);
    G0 = (sq & 2) ? h1_ : m0; G1 = (sq & 2) ? h2_ : m1;
    G2 = (sq & 2) ? m2 : h1_; G3 = (sq & 2) ? m3 : h2_;
}

#define PIN8(A,B,C,D,E,F,G,H) \
    asm volatile("" : "+v"(A),"+v"(B),"+v"(C),"+v"(D),"+v"(E),"+v"(F),"+v"(G),"+v"(H))
#define SBAR()  __builtin_amdgcn_sched_barrier(0)
#define MEMBAR() asm volatile("" ::: "memory")
#define RAWBAR() do { MEMBAR(); SBAR(); __builtin_amdgcn_s_barrier(); SBAR(); MEMBAR(); } while (0)

// Persistent dilated-LSTM, grid 256, XCD-clustered (cid = bid&7, w = bid>>3).
// r8-r11 PROVEN: plain-store -> global_load_lds is FRESH intra-cluster (same
// XCD L2); sc0 loads are NOT (can hit stale L1) - R8/R9/R11 escalations.
// So the fast iflag poll now uses the PROVEN instruction class:
//   publish: plain global_store_dword (XCD L2) + sc1 MALL mirror
//   poll:    lanes 0-7 global_load_lds the 128B flag line -> LDS scratch,
//            vmcnt(0), volatile ds_read, __all((v - t) <= 1) exact-match
//            (wg skew provably <=1; stale prev-replay values <= T rejected
//            for t < T-1; t == T-1 gates via MALL mirror). 1024-iter
//            escalation -> permanent MALL fallback (bounded worst case).
// Wave roles / barriers / release: identical to r11 (race-free, verified):
//   w0 iflag poll + x-stage | w1 cflag poll + x-stage | w2/w3 h-stage + publish
//   B0/B1/B2 raw barriers, per-wave counted self-drains; h plain stores
//   gated by counted vmcnt; Xq sc1 copies published one step late (cflag).
__global__ __launch_bounds__(256, 1) void k_drnn(DP p) {
    const int tid = threadIdx.x, lane = tid & 63, wv = tid >> 6;
    const int l15 = lane & 15, lhi = lane >> 4, sq = l15 & 3;

    const int b = blockIdx.x;
    const int cid = b & 7, w = b >> 3;
    int l, c, T, P, N;
    if (cid < 2)      { l = 0; c = cid;     T = 256; P = 1; N = 64;  }
    else if (cid < 4) { l = 1; c = cid - 2; T = 128; P = 2; N = 128; }
    else              { l = 2; c = cid - 4; T = 64;  P = 2; N = 256; }

    const unsigned short* Xs = (l == 0) ? p.Xp  : (l == 1 ? p.Xq1 : p.Xq2);
    unsigned short*       Hd = (l == 0) ? p.Hp0 : (l == 1 ? p.Hp1 : p.Hp2);
    unsigned short*       Xw = (l == 0) ? p.Xq1 : (l == 1 ? p.Xq2 : nullptr);
    const unsigned short* Ws = (l == 0) ? p.Wp0 : (l == 1 ? p.Wp1 : p.Wp2);
    const float* bi = (l == 0) ? p.bi0 : (l == 1 ? p.bi1 : p.bi2);
    const float* bh = (l == 0) ? p.bh0 : (l == 1 ? p.bh1 : p.bh2);
    const int R0 = c * (P * 32);
    const int alias = (p.Xq1 == p.Hp0);

    __shared__ unsigned short At[65536];   // 128 KiB
    __shared__ unsigned pollbuf[32];       // 128 B flag-line scratch

    const unsigned short* wbase = Ws + ((size_t)(((w << 2) + wv) * 32) << 9) + lane * 8;
#define DECLW(n) bf16x8 w##n = *(const bf16x8*)(wbase + (n << 9));
    DECLW(0) DECLW(1) DECLW(2) DECLW(3) DECLW(4) DECLW(5) DECLW(6) DECLW(7)
    DECLW(8) DECLW(9) DECLW(10) DECLW(11) DECLW(12) DECLW(13) DECLW(14) DECLW(15)
    DECLW(16) DECLW(17) DECLW(18) DECLW(19) DECLW(20) DECLW(21) DECLW(22) DECLW(23)
    DECLW(24) DECLW(25) DECLW(26) DECLW(27) DECLW(28) DECLW(29) DECLW(30) DECLW(31)

    const int hcol = (w << 4) + (wv << 2) + (l15 >> 2);
    const float bs0 = bi[hcol]        + bh[hcol];
    const float bs1 = bi[512 + hcol]  + bh[512 + hcol];
    const float bs2 = bi[1024 + hcol] + bh[1024 + hcol];
    const float bs3 = bi[1536 + hcol] + bh[1536 + hcol];

    const int kch = hcol >> 5;
    const int lane16 = (((hcol & 31) >> 3) << 4) + ((lhi << 2) + sq);
    const int st_lt = lane16 * 8 + (hcol & 7);

    float cst0 = 0.f, cst1 = 0.f, cst2 = 0.f, cst3 = 0.f;
    unsigned int* iflagV = p.flags;
    unsigned int* mflagV = p.flags + 256;
    unsigned int* cflagS = p.flags + 512;
    int fastok = 1;

#define KPn(na, nb) { \
    bf16x8 xa = *(const bf16x8*)(a0 + ((na) << 9)); \
    bf16x8 xb = *(const bf16x8*)(a1 + ((na) << 9)); \
    bf16x8 ya = *(const bf16x8*)(a0 + ((nb) << 9)); \
    bf16x8 yb = *(const bf16x8*)(a1 + ((nb) << 9)); \
    e0 = __builtin_amdgcn_mfma_f32_16x16x32_bf16(xa, w##na, e0, 0, 0, 0); \
    e1 = __builtin_amdgcn_mfma_f32_16x16x32_bf16(xb, w##na, e1, 0, 0, 0); \
    o0 = __builtin_amdgcn_mfma_f32_16x16x32_bf16(ya, w##nb, o0, 0, 0, 0); \
    o1 = __builtin_amdgcn_mfma_f32_16x16x32_bf16(yb, w##nb, o1, 0, 0, 0); }

#define PWC(RV, CSTV, HV) { \
    float G0, G1, G2, G3; quadT(RV, sq, G0, G1, G2, G3); \
    float cn = sigm(G1 + bs1) * CSTV + sigm(G0 + bs0) * ftanh(G2 + bs2); \
    HV = sigm(G3 + bs3) * ftanh(cn); CSTV = cn; }

#define DOPASS(PI, CA, CB, HA, HB) { \
    const unsigned short* a0 = At + (((PI) * 64) << 9) + lane * 8; \
    const unsigned short* a1 = a0 + (32 << 9); \
    f32x4 e0 = {0.f,0.f,0.f,0.f}, o0 = {0.f,0.f,0.f,0.f}; \
    f32x4 e1 = {0.f,0.f,0.f,0.f}, o1 = {0.f,0.f,0.f,0.f}; \
    KPn(0,1) KPn(2,3) KPn(4,5) KPn(6,7) KPn(8,9) KPn(10,11) KPn(12,13) KPn(14,15) \
    KPn(16,17) KPn(18,19) KPn(20,21) KPn(22,23) KPn(24,25) KPn(26,27) KPn(28,29) KPn(30,31) \
    f32x4 r0 = e0 + o0, r1 = e1 + o1; \
    PWC(r0, CA, HA) PWC(r1, CB, HB) }

    for (int t = 0; t < T; ++t) {
        PIN8(w0,w1,w2,w3,w4,w5,w6,w7);
        PIN8(w8,w9,w10,w11,w12,w13,w14,w15);
        PIN8(w16,w17,w18,w19,w20,w21,w22,w23);
        PIN8(w24,w25,w26,w27,w28,w29,w30,w31);

        const int RxB = (t * N + R0) >> 4;

        // L0: waves 0/1 prefetch ALL x chunks (static input) before the polls
        if (l == 0 && wv < 2) {
            #pragma unroll
            for (int i = 0; i < 16; ++i) {
                int q = (wv << 4) + i, rb = q >> 4, kc = q & 15;
                gld16(Xs + ((size_t)((RxB + rb) * 16 + kc) << 9) + lane * 8,
                      &At[(rb * 32 + kc) << 9]);
            }
        }

        // ---- wave0: own-cluster iflag poll
        if (wv == 0 && t > 0) {
            const unsigned need = (unsigned)t;
            const unsigned* mp = mflagV + cid * 32 + (lane & 31);
            if (t == T - 1 || !fastok) {            // authoritative MALL gate
                int n = 0;
                while (!__all(ld_mall(mp) >= need)) { if (++n > (1 << 22)) break; }
            } else {
                // FAST PATH: poll via global_load_lds (the r8-proven-fresh class)
                const unsigned short* gip = (const unsigned short*)(iflagV + cid * 32);
                volatile unsigned* pb = pollbuf;
                int n = 0;
                for (;;) {
                    if (lane < 8) gld16(gip + lane * 8, (unsigned short*)pollbuf);
                    asm volatile("s_waitcnt vmcnt(0)" ::: "memory");
                    SBAR();
                    unsigned v = pb[lane & 31];
                    if (__all((v - need) <= 1u)) break;
                    if (++n > 1024) {
                        fastok = 0;                 // permanent, bounded fallback
                        int m = 0;
                        while (!__all(ld_mall(mp) >= need)) { if (++m > (1 << 22)) break; }
                        break;
                    }
                }
            }
        }
        // ---- wave1: cross-layer cflag poll (MALL sums, r9-verified formulas)
        if (l == 1 && wv == 1 && lane < 2) {
            const unsigned* cp = cflagS + lane * 32;
            const unsigned need = 32u * (unsigned)(2 * t + c + 1);
            int n = 0;
            while (!__all(ld_mall(cp) >= need)) { if (++n > (1 << 22)) break; }
        }
        if (l == 2 && wv == 1 && lane == 0) {
            const unsigned* cp = cflagS + (2 + (c & 1)) * 32;
            const unsigned need = 32u * (unsigned)(2 * t + (c >> 1) + 1);
            int n = 0;
            while (ld_mall(cp) < need) { if (++n > (1 << 22)) break; }
        }
        if (wv < 2) asm volatile("s_waitcnt vmcnt(0)" ::: "memory");  // x staged (own)
        RAWBAR();                                                     // B0

        float hv0, hv1, hv2 = 0.f, hv3 = 0.f;
        if (l == 0) {
            if (t > 0) {
                if (wv >= 2) {                       // h-stage by publisher waves
                    const int RhB = ((t - 1) * N + R0) >> 4;
                    #pragma unroll
                    for (int i = 0; i < 16; ++i) {
                        int q = ((wv - 2) << 4) + i, rb = q >> 4, kc = q & 15;
                        gld16(Hd + ((size_t)((RhB + rb) * 16 + kc) << 9) + lane * 8,
                              &At[(rb * 32 + 16 + kc) << 9]);
                    }
                }
            } else {
                #pragma unroll
                for (int rb = 0; rb < 2; ++rb)
                    #pragma unroll
                    for (int it = 0; it < 4; ++it)
                        *(float4*)&At[((rb * 32 + 16) << 9) + (it * 256 + tid) * 8] =
                            (float4){0.f, 0.f, 0.f, 0.f};
            }
            SBAR();
            // x-half MFMAs run while h loads fly
            const unsigned short* a0 = At + lane * 8;
            const unsigned short* a1 = a0 + (32 << 9);
            f32x4 e0 = {0.f,0.f,0.f,0.f}, o0 = {0.f,0.f,0.f,0.f};
            f32x4 e1 = {0.f,0.f,0.f,0.f}, o1 = {0.f,0.f,0.f,0.f};
            KPn(0,1) KPn(2,3) KPn(4,5) KPn(6,7)
            KPn(8,9) KPn(10,11) KPn(12,13) KPn(14,15)
            if (wv >= 2) asm volatile("s_waitcnt vmcnt(0)" ::: "memory");  // h staged (own)
            asm volatile("s_waitcnt lgkmcnt(0)" ::: "memory");             // t==0 zero-fill
            RAWBAR();                                                      // B1
            KPn(16,17) KPn(18,19) KPn(20,21) KPn(22,23)
            KPn(24,25) KPn(26,27) KPn(28,29) KPn(30,31)
            f32x4 r0 = e0 + o0, r1 = e1 + o1;
            PWC(r0, cst0, hv0) PWC(r1, cst1, hv1)
        } else {
            if (wv < 2) {                            // x-stage (flag-gated)
                #pragma unroll
                for (int i = 0; i < 32; ++i) {
                    int q = (wv << 5) + i, rb = q >> 4, kc = q & 15;
                    gld16(Xs + ((size_t)((RxB + rb) * 16 + kc) << 9) + lane * 8,
                          &At[(rb * 32 + kc) << 9]);
                }
            }
            if (t > 0) {
                if (wv >= 2) {                       // h-stage
                    const int RhB = ((t - 1) * N + R0) >> 4;
                    #pragma unroll
                    for (int i = 0; i < 32; ++i) {
                        int q = ((wv - 2) << 5) + i, rb = q >> 4, kc = q & 15;
                        gld16(Hd + ((size_t)((RhB + rb) * 16 + kc) << 9) + lane * 8,
                              &At[(rb * 32 + 16 + kc) << 9]);
                    }
                }
            } else {
                #pragma unroll
                for (int rb = 0; rb < 4; ++rb)
                    #pragma unroll
                    for (int it = 0; it < 4; ++it)
                        *(float4*)&At[((rb * 32 + 16) << 9) + (it * 256 + tid) * 8] =
                            (float4){0.f, 0.f, 0.f, 0.f};
            }
            asm volatile("s_waitcnt vmcnt(0)" ::: "memory");   // own stage drained
            asm volatile("s_waitcnt lgkmcnt(0)" ::: "memory");
            RAWBAR();                                           // B1
            DOPASS(0, cst0, cst1, hv0, hv1)
            DOPASS(1, cst2, cst3, hv2, hv3)
        }

        // ---- release: plain h, (Out), then sc1 Xq; counted wait = h acks only
        const unsigned short hb0 = f2bf(hv0), hb1 = f2bf(hv1);
        const unsigned short hb2 = f2bf(hv2), hb3 = f2bf(hv3);
        const size_t i0 = ((size_t)((RxB + 0) * 16 + kch) << 9) + st_lt;
        const size_t i1 = ((size_t)((RxB + 1) * 16 + kch) << 9) + st_lt;
        const size_t i2 = ((size_t)((RxB + 2) * 16 + kch) << 9) + st_lt;
        const size_t i3 = ((size_t)((RxB + 3) * 16 + kch) << 9) + st_lt;
        if (!alias || l == 2) {
            Hd[i0] = hb0; Hd[i1] = hb1;
            if (P == 2) { Hd[i2] = hb2; Hd[i3] = hb3; }
        }
        if (l == 2) {
            p.Out[((size_t)(((RxB + 0) << 4) + (lhi << 2) + sq)) * 512 + hcol] = hv0;
            p.Out[((size_t)(((RxB + 1) << 4) + (lhi << 2) + sq)) * 512 + hcol] = hv1;
            p.Out[((size_t)(((RxB + 2) << 4) + (lhi << 2) + sq)) * 512 + hcol] = hv2;
            p.Out[((size_t)(((RxB + 3) << 4) + (lhi << 2) + sq)) * 512 + hcol] = hv3;
        }
        MEMBAR(); SBAR();
        if (l == 0) { st_wt16(Xw + i0, hb0); st_wt16(Xw + i1, hb1); }
        else if (l == 1) { st_wt16(Xw + i0, hb0); st_wt16(Xw + i1, hb1);
                           st_wt16(Xw + i2, hb2); st_wt16(Xw + i3, hb3); }
        SBAR();
        if (alias && l < 2)  asm volatile("s_waitcnt vmcnt(0)" ::: "memory");
        else if (l == 0)     asm volatile("s_waitcnt vmcnt(2)" ::: "memory");  // h acked
        else                 asm volatile("s_waitcnt vmcnt(4)" ::: "memory");  // h acked
        RAWBAR();                                           // B2
        // publishers: fire-and-forget; acks retire before their next B1 drain
        if (tid == 192) {
            st_plain32(iflagV + cid * 32 + w, (unsigned)(t + 1));   // XCD L2 fast path
            st_wt32(mflagV + cid * 32 + w, (unsigned)(t + 1));      // MALL mirror
        }
        if (tid == 128 && l < 2 && t > 0) aaddMALL(cflagS + cid * 32);  // steps <= t-1
    }

    asm volatile("s_waitcnt vmcnt(0)" ::: "memory");
    __builtin_amdgcn_s_barrier();
    if (tid == 128 && l < 2) aaddMALL(cflagS + cid * 32);           // all T visible
}

extern "C" void kernel_launch(void* const* d_in, const int* in_sizes, int n_in,
                              void* d_out, int out_size, void* d_ws, size_t ws_size,
                              hipStream_t stream)
{
    const float* x = (const float*)d_in[0];
    const float* Wih[3] = {(const float*)d_in[1], (const float*)d_in[5], (const float*)d_in[9]};
    const float* Whh[3] = {(const float*)d_in[2], (const float*)d_in[6], (const float*)d_in[10]};
    const float* bih[3] = {(const float*)d_in[3], (const float*)d_in[7], (const float*)d_in[11]};
    const float* bhh[3] = {(const float*)d_in[4], (const float*)d_in[8], (const float*)d_in[12]};

    char* wp = (char*)d_ws;
    const size_t SZ_A = (size_t)16384 * 512;
    unsigned int* flags = (unsigned int*)wp; wp += 4096;
    unsigned short* Xp  = (unsigned short*)wp; wp += SZ_A * 2;
    unsigned short* Hp0 = (unsigned short*)wp; wp += SZ_A * 2;
    unsigned short* Hp1 = (unsigned short*)wp; wp += SZ_A * 2;
    unsigned short* Hp2 = (unsigned short*)wp; wp += SZ_A * 2;
    unsigned short* Wp[3];
    for (int l = 0; l < 3; ++l) { Wp[l] = (unsigned short*)wp; wp += (size_t)2048 * 1024 * 2; }
    unsigned short* Xq1 = (unsigned short*)wp; wp += SZ_A * 2;
    unsigned short* Xq2 = (unsigned short*)wp; wp += SZ_A * 2;
    const size_t need = (size_t)(wp - (char*)d_ws);
    if (ws_size < need) { Xq1 = Hp0; Xq2 = Hp1; }   // fallback: sc1-only h path

    hipMemsetAsync(flags, 0, 4096, stream);
    k_conv_x<<<dim3(4096), dim3(256), 0, stream>>>(x, Xp);
    for (int l = 0; l < 3; ++l)
        k_conv_w<<<dim3(1024), dim3(256), 0, stream>>>(Wih[l], Whh[l], Wp[l]);

    DP dp;
    dp.Xp = Xp; dp.Hp0 = Hp0; dp.Hp1 = Hp1; dp.Hp2 = Hp2;
    dp.Xq1 = Xq1; dp.Xq2 = Xq2;
    dp.Wp0 = Wp[0]; dp.Wp1 = Wp[1]; dp.Wp2 = Wp[2];
    dp.bi0 = bih[0]; dp.bh0 = bhh[0];
    dp.bi1 = bih[1]; dp.bh1 = bhh[1];
    dp.bi2 = bih[2]; dp.bh2 = bhh[2];
    dp.Out = (float*)d_out; dp.flags = flags;

    k_drnn<<<dim3(256), dim3(256), 0, stream>>>(dp);
}

// Round 15
// 934.243 us; speedup vs baseline: 1.9349x; 1.0185x over previous
//
#include <hip/hip_runtime.h>

typedef __attribute__((ext_vector_type(8))) short bf16x8;
typedef __attribute__((ext_vector_type(4))) float f32x4;

__device__ __forceinline__ unsigned short f2bf(float x) {
    unsigned u = __float_as_uint(x);
    u += 0x7FFFu + ((u >> 16) & 1u);
    return (unsigned short)(u >> 16);
}
__device__ __forceinline__ float sigm(float x) { return 1.0f / (1.0f + __expf(-x)); }
__device__ __forceinline__ float ftanh(float x) {
    float e = __expf(2.f * x);
    return 1.f - 2.f / (e + 1.f);
}

// async global->LDS, 16B/lane, wave-uniform LDS base + lane*16
__device__ __forceinline__ void gld16(const unsigned short* g, unsigned short* l) {
    __builtin_amdgcn_global_load_lds((const __attribute__((address_space(1))) void*)g,
                                     (__attribute__((address_space(3))) void*)l, 16, 0, 0);
}

// ---- flag primitives ----
__device__ __forceinline__ void st_plain32(unsigned* p, unsigned v) {  // -> XCD L2 (write-through)
    asm volatile("global_store_dword %0, %1, off" :: "v"(p), "v"(v) : "memory");
}
__device__ __forceinline__ void st_wt32(unsigned* p, unsigned v) {     // -> MALL
    asm volatile("global_store_dword %0, %1, off sc0 sc1" :: "v"(p), "v"(v) : "memory");
}
__device__ __forceinline__ void aaddMALL(unsigned* p) {
    unsigned one = 1;
    asm volatile("global_atomic_add %0, %1, off sc1" :: "v"(p), "v"(one) : "memory");
}
__device__ __forceinline__ unsigned ld_mall(const unsigned* p) {       // read MALL
    unsigned v;
    asm volatile("global_load_dword %0, %1, off sc0 sc1\n\ts_waitcnt vmcnt(0)"
                 : "=v"(v) : "v"(p) : "memory");
    return v;
}
__device__ __forceinline__ void st_wt16(unsigned short* p, unsigned v) {
    asm volatile("global_store_short %0, %1, off sc0 sc1" :: "v"(p), "v"(v) : "memory");
}

// DPP quad-lane exchanges (1-cycle VALU)
__device__ __forceinline__ float dppx1(float x) {
    return __int_as_float(__builtin_amdgcn_mov_dpp(__float_as_int(x), 0xB1, 0xF, 0xF, true));
}
__device__ __forceinline__ float dppx2(float x) {
    return __int_as_float(__builtin_amdgcn_mov_dpp(__float_as_int(x), 0x4E, 0xF, 0xF, true));
}

// ---------------- packing kernels (round-6-verified) ----------------
__global__ __launch_bounds__(256) void k_conv_x(const float* __restrict__ x,
                                                unsigned short* __restrict__ Xp) {
    int i = blockIdx.x * 256 + threadIdx.x;
    int rb = i >> 10, kc = (i >> 6) & 15, ln = i & 63;
    int row = (rb << 4) + (ln & 15);
    int k   = (kc << 5) + ((ln >> 4) << 3);
    const float* s = x + (size_t)row * 512 + k;
    float4 v0 = *(const float4*)s, v1 = *(const float4*)(s + 4);
    unsigned short o[8] = {f2bf(v0.x), f2bf(v0.y), f2bf(v0.z), f2bf(v0.w),
                           f2bf(v1.x), f2bf(v1.y), f2bf(v1.z), f2bf(v1.w)};
    *(bf16x8*)(Xp + (size_t)i * 8) = *(bf16x8*)o;
}

__global__ __launch_bounds__(256) void k_conv_w(const float* __restrict__ Wih,
                                                const float* __restrict__ Whh,
                                                unsigned short* __restrict__ Wp) {
    int i = blockIdx.x * 256 + threadIdx.x;
    int wrb = i >> 11, kc = (i >> 6) & 31, ln = i & 63;
    int j = (wrb << 4) + (ln & 15);
    int k = (kc << 5) + ((ln >> 4) << 3);
    int srow = (j & 3) * 512 + (j >> 2);              // torch row g*512+hc
    const float* s = (k < 512) ? (Wih + (size_t)srow * 512 + k)
                               : (Whh + (size_t)srow * 512 + (k - 512));
    float4 v0 = *(const float4*)s, v1 = *(const float4*)(s + 4);
    unsigned short o[8] = {f2bf(v0.x), f2bf(v0.y), f2bf(v0.z), f2bf(v0.w),
                           f2bf(v1.x), f2bf(v1.y), f2bf(v1.z), f2bf(v1.w)};
    *(bf16x8*)(Wp + (size_t)i * 8) = *(bf16x8*)o;
}

struct DP {
    const unsigned short* Xp;
    unsigned short *Hp0, *Hp1, *Hp2;
    unsigned short *Xq1, *Xq2;
    const unsigned short *Wp0, *Wp1, *Wp2;
    const float *bi0, *bh0, *bi1, *bh1, *bi2, *bh2;
    float* Out;
    unsigned int* flags;   // [0,256) iflagV, [256,512) mflagV, [512,768) cflagS
};

__device__ __forceinline__ void quadT(f32x4 a, int sq, float& G0, float& G1, float& G2, float& G3) {
    float a0 = a[0], a1 = a[1], a2 = a[2], a3 = a[3];
    float p1 = (sq & 1) ? a0 : a1; float g1_ = dppx1(p1);
    float p2 = (sq & 1) ? a2 : a3; float g2_ = dppx1(p2);
    float m0 = (sq & 1) ? g1_ : a0, m1 = (sq & 1) ? a1 : g1_;
    float m2 = (sq & 1) ? g2_ : a2, m3 = (sq & 1) ? a3 : g2_;
    float q1 = (sq & 2) ? m0 : m2; float h1_ = dppx2(q1);
    float q2 = (sq & 2) ? m1 : m3; float h2_ = dppx2(q2);
    G0 = (sq & 2) ? h1_ : m0; G1 = (sq & 2) ? h2_ : m1;
    G2 = (sq & 2) ? m2 : h1_; G3 = (sq & 2) ? m3 : h2_;
}

#define PIN8(A,B,C,D,E,F,G,H) \
    asm volatile("" : "+v"(A),"+v"(B),"+v"(C),"+v"(D),"+v"(E),"+v"(F),"+v"(G),"+v"(H))
#define SBAR()  __builtin_amdgcn_sched_barrier(0)
#define MEMBAR() asm volatile("" ::: "memory")
#define RAWBAR() do { MEMBAR(); SBAR(); __builtin_amdgcn_s_barrier(); SBAR(); MEMBAR(); } while (0)

// Persistent dilated-LSTM, grid 256, XCD-clustered (cid = bid&7, w = bid>>3).
// ROTATED PIPELINE, r14 bugs fixed:
//  (1) l>0 shadow: CPOLL gate now followed by RAWBAR before STAGE_X (r14
//      raced: waves 0/2/3 staged producer data before wave1's gate).
//  (2) vmcnt retires IN ISSUE ORDER -> counted exclusion only works if the
//      publish stores are issued AFTER the stage gld16s. l==0 shadow now:
//      STAGE_X, then publish, then w3 vmcnt(2) / w2 vmcnt(1). l>0: publish
//      first (pre-gate), vmcnt(0) for all (producer-paced, off-chain).
//  (3) publish counts: epilogue publishes iflag/mirror = T (restores the
//      >=2 stale-reject margin at t=T-2) and TWO cflag adds -> sum 32*T
//      (r14 came up 32 short -> every L1/L2 tail step burned the escape).
// Flag mechanisms otherwise = r13 (proven): plain-store publish + gld16
// poll (exact-match (v-t)<=1; t==T-1 via MALL mirror; 1024-iter permanent
// escalation); cflag = MALL sums, one step delayed, r9-verified formulas.
__global__ __launch_bounds__(256, 1) void k_drnn(DP p) {
    const int tid = threadIdx.x, lane = tid & 63, wv = tid >> 6;
    const int l15 = lane & 15, lhi = lane >> 4, sq = l15 & 3;

    const int b = blockIdx.x;
    const int cid = b & 7, w = b >> 3;
    int l, c, T, P, N;
    if (cid < 2)      { l = 0; c = cid;     T = 256; P = 1; N = 64;  }
    else if (cid < 4) { l = 1; c = cid - 2; T = 128; P = 2; N = 128; }
    else              { l = 2; c = cid - 4; T = 64;  P = 2; N = 256; }

    const unsigned short* Xs = (l == 0) ? p.Xp  : (l == 1 ? p.Xq1 : p.Xq2);
    unsigned short*       Hd = (l == 0) ? p.Hp0 : (l == 1 ? p.Hp1 : p.Hp2);
    unsigned short*       Xw = (l == 0) ? p.Xq1 : (l == 1 ? p.Xq2 : nullptr);
    const unsigned short* Ws = (l == 0) ? p.Wp0 : (l == 1 ? p.Wp1 : p.Wp2);
    const float* bi = (l == 0) ? p.bi0 : (l == 1 ? p.bi1 : p.bi2);
    const float* bh = (l == 0) ? p.bh0 : (l == 1 ? p.bh1 : p.bh2);
    const int R0 = c * (P * 32);
    const int alias = (p.Xq1 == p.Hp0);

    __shared__ unsigned short At[65536];   // 128 KiB
    __shared__ unsigned pollbuf[32];       // flag-line scratch

    const unsigned short* wbase = Ws + ((size_t)(((w << 2) + wv) * 32) << 9) + lane * 8;
#define DECLW(n) bf16x8 w##n = *(const bf16x8*)(wbase + (n << 9));
    DECLW(0) DECLW(1) DECLW(2) DECLW(3) DECLW(4) DECLW(5) DECLW(6) DECLW(7)
    DECLW(8) DECLW(9) DECLW(10) DECLW(11) DECLW(12) DECLW(13) DECLW(14) DECLW(15)
    DECLW(16) DECLW(17) DECLW(18) DECLW(19) DECLW(20) DECLW(21) DECLW(22) DECLW(23)
    DECLW(24) DECLW(25) DECLW(26) DECLW(27) DECLW(28) DECLW(29) DECLW(30) DECLW(31)

    const int hcol = (w << 4) + (wv << 2) + (l15 >> 2);
    const float bs0 = bi[hcol]        + bh[hcol];
    const float bs1 = bi[512 + hcol]  + bh[512 + hcol];
    const float bs2 = bi[1024 + hcol] + bh[1024 + hcol];
    const float bs3 = bi[1536 + hcol] + bh[1536 + hcol];

    const int kch = hcol >> 5;
    const int lane16 = (((hcol & 31) >> 3) << 4) + ((lhi << 2) + sq);
    const int st_lt = lane16 * 8 + (hcol & 7);

    float cst0 = 0.f, cst1 = 0.f, cst2 = 0.f, cst3 = 0.f;
    unsigned int* iflagV = p.flags;
    unsigned int* mflagV = p.flags + 256;
    unsigned int* cflagS = p.flags + 512;
    int fastok = 1;

#define KPX(na, nb, E0, E1, O0, O1, A0, A1) { \
    bf16x8 xa = *(const bf16x8*)((A0) + ((na) << 9)); \
    bf16x8 xb = *(const bf16x8*)((A1) + ((na) << 9)); \
    bf16x8 ya = *(const bf16x8*)((A0) + ((nb) << 9)); \
    bf16x8 yb = *(const bf16x8*)((A1) + ((nb) << 9)); \
    E0 = __builtin_amdgcn_mfma_f32_16x16x32_bf16(xa, w##na, E0, 0, 0, 0); \
    E1 = __builtin_amdgcn_mfma_f32_16x16x32_bf16(xb, w##na, E1, 0, 0, 0); \
    O0 = __builtin_amdgcn_mfma_f32_16x16x32_bf16(ya, w##nb, O0, 0, 0, 0); \
    O1 = __builtin_amdgcn_mfma_f32_16x16x32_bf16(yb, w##nb, O1, 0, 0, 0); }

#define XH(E0, E1, O0, O1, A0, A1) \
    KPX(0,1,E0,E1,O0,O1,A0,A1) KPX(2,3,E0,E1,O0,O1,A0,A1) \
    KPX(4,5,E0,E1,O0,O1,A0,A1) KPX(6,7,E0,E1,O0,O1,A0,A1) \
    KPX(8,9,E0,E1,O0,O1,A0,A1) KPX(10,11,E0,E1,O0,O1,A0,A1) \
    KPX(12,13,E0,E1,O0,O1,A0,A1) KPX(14,15,E0,E1,O0,O1,A0,A1)
#define HH(E0, E1, O0, O1, A0, A1) \
    KPX(16,17,E0,E1,O0,O1,A0,A1) KPX(18,19,E0,E1,O0,O1,A0,A1) \
    KPX(20,21,E0,E1,O0,O1,A0,A1) KPX(22,23,E0,E1,O0,O1,A0,A1) \
    KPX(24,25,E0,E1,O0,O1,A0,A1) KPX(26,27,E0,E1,O0,O1,A0,A1) \
    KPX(28,29,E0,E1,O0,O1,A0,A1) KPX(30,31,E0,E1,O0,O1,A0,A1)

#define PWC(RV, CSTV, HV) { \
    float G0, G1, G2, G3; quadT(RV, sq, G0, G1, G2, G3); \
    float cn = sigm(G1 + bs1) * CSTV + sigm(G0 + bs0) * ftanh(G2 + bs2); \
    HV = sigm(G3 + bs3) * ftanh(cn); CSTV = cn; }

#define STAGE_X(TT) { \
    const int RxN = ((TT) * N + R0) >> 4; \
    for (int i = 0; i < P * 8; ++i) { \
        int q = wv * (P * 8) + i, rb = q >> 4, kc = q & 15; \
        gld16(Xs + ((size_t)((RxN + rb) * 16 + kc) << 9) + lane * 8, \
              &At[(rb * 32 + kc) << 9]); } }
#define STAGE_H(TT) { \
    const int RhN = ((TT) * N + R0) >> 4; \
    for (int i = 0; i < P * 8; ++i) { \
        int q = wv * (P * 8) + i, rb = q >> 4, kc = q & 15; \
        gld16(Hd + ((size_t)((RhN + rb) * 16 + kc) << 9) + lane * 8, \
              &At[(rb * 32 + 16 + kc) << 9]); } }

#define CPOLL(TT) { \
    if (l == 1 && wv == 1 && lane < 2) { \
        const unsigned* cp = cflagS + lane * 32; \
        const unsigned need = 32u * (unsigned)(2 * (TT) + c + 1); \
        int n = 0; \
        while (!__all(ld_mall(cp) >= need)) { if (++n > (1 << 22)) break; } \
    } \
    if (l == 2 && wv == 1 && lane == 0) { \
        const unsigned* cp = cflagS + (2 + (c & 1)) * 32; \
        const unsigned need = 32u * (unsigned)(2 * (TT) + (c >> 1) + 1); \
        int n = 0; \
        while (ld_mall(cp) < need) { if (++n > (1 << 22)) break; } \
    } }

    f32x4 e0 = {0,0,0,0}, e1 = {0,0,0,0}, o0 = {0,0,0,0}, o1 = {0,0,0,0};
    f32x4 e2 = {0,0,0,0}, e3 = {0,0,0,0}, o2 = {0,0,0,0}, o3 = {0,0,0,0};
    const unsigned short* A00 = At + lane * 8;
    const unsigned short* A01 = A00 + (32 << 9);
    const unsigned short* A10 = A00 + (64 << 9);
    const unsigned short* A11 = A00 + (96 << 9);

    // ---------- prologue: x(0) staged + x-half partials ----------
    if (l > 0) CPOLL(0);
    RAWBAR();
    STAGE_X(0);
    asm volatile("s_waitcnt vmcnt(0)" ::: "memory");
    RAWBAR();
    { XH(e0, e1, o0, o1, A00, A01) }
    if (P == 2) { XH(e2, e3, o2, o3, A10, A11) }

    for (int t = 0; t < T; ++t) {
        PIN8(w0,w1,w2,w3,w4,w5,w6,w7);
        PIN8(w8,w9,w10,w11,w12,w13,w14,w15);
        PIN8(w16,w17,w18,w19,w20,w21,w22,w23);
        PIN8(w24,w25,w26,w27,w28,w29,w30,w31);

        const int RxB = (t * N + R0) >> 4;

        if (t > 0) {
            // ---- wave0: own-cluster iflag poll (flag published early in the
            // previous shadow -> ~full x-section of flight time)
            if (wv == 0) {
                const unsigned need = (unsigned)t;
                const unsigned* mp = mflagV + cid * 32 + (lane & 31);
                if (t == T - 1 || !fastok) {         // authoritative MALL gate
                    int n = 0;
                    while (!__all(ld_mall(mp) >= need)) { if (++n > (1 << 22)) break; }
                } else {
                    const unsigned short* gip = (const unsigned short*)(iflagV + cid * 32);
                    volatile unsigned* pb = pollbuf;
                    int n = 0;
                    for (;;) {
                        if (lane < 8) gld16(gip + lane * 8, (unsigned short*)pollbuf);
                        asm volatile("s_waitcnt vmcnt(0)" ::: "memory");
                        SBAR();
                        unsigned v = pb[lane & 31];
                        if (__all((v - need) <= 1u)) break;
                        if (++n > 1024) {
                            fastok = 0;
                            int m = 0;
                            while (!__all(ld_mall(mp) >= need)) { if (++m > (1 << 22)) break; }
                            break;
                        }
                    }
                }
            }
            RAWBAR();                                 // B0: h(t-1) ready
            STAGE_H(t - 1);                           // all 4 waves
            asm volatile("s_waitcnt vmcnt(0)" ::: "memory");
            RAWBAR();                                 // B1: h staged
            { HH(e0, e1, o0, o1, A00, A01) }          // accumulate onto x-partials
            if (P == 2) { HH(e2, e3, o2, o3, A10, A11) }
        }

        // ---- pointwise + stores
        float hv0, hv1, hv2 = 0.f, hv3 = 0.f;
        { f32x4 r0 = e0 + o0, r1 = e1 + o1;
          PWC(r0, cst0, hv0) PWC(r1, cst1, hv1) }
        if (P == 2) {
          f32x4 r2 = e2 + o2, r3 = e3 + o3;
          PWC(r2, cst2, hv2) PWC(r3, cst3, hv3) }

        const unsigned short hb0 = f2bf(hv0), hb1 = f2bf(hv1);
        const unsigned short hb2 = f2bf(hv2), hb3 = f2bf(hv3);
        const size_t i0 = ((size_t)((RxB + 0) * 16 + kch) << 9) + st_lt;
        const size_t i1 = ((size_t)((RxB + 1) * 16 + kch) << 9) + st_lt;
        const size_t i2 = ((size_t)((RxB + 2) * 16 + kch) << 9) + st_lt;
        const size_t i3 = ((size_t)((RxB + 3) * 16 + kch) << 9) + st_lt;
        if (!alias || l == 2) {
            Hd[i0] = hb0; Hd[i1] = hb1;
            if (P == 2) { Hd[i2] = hb2; Hd[i3] = hb3; }
        }
        if (l == 2) {
            p.Out[((size_t)(((RxB + 0) << 4) + (lhi << 2) + sq)) * 512 + hcol] = hv0;
            p.Out[((size_t)(((RxB + 1) << 4) + (lhi << 2) + sq)) * 512 + hcol] = hv1;
            p.Out[((size_t)(((RxB + 2) << 4) + (lhi << 2) + sq)) * 512 + hcol] = hv2;
            p.Out[((size_t)(((RxB + 3) << 4) + (lhi << 2) + sq)) * 512 + hcol] = hv3;
        }
        MEMBAR(); SBAR();
        if (l == 0) { st_wt16(Xw + i0, hb0); st_wt16(Xw + i1, hb1); }
        else if (l == 1) { st_wt16(Xw + i0, hb0); st_wt16(Xw + i1, hb1);
                           st_wt16(Xw + i2, hb2); st_wt16(Xw + i3, hb3); }
        SBAR();
        if (alias && l < 2)  asm volatile("s_waitcnt vmcnt(0)" ::: "memory");
        else if (l == 0)     asm volatile("s_waitcnt vmcnt(2)" ::: "memory");  // h acked
        else                 asm volatile("s_waitcnt vmcnt(4)" ::: "memory");  // h acked
        RAWBAR();                                     // B2

        // ---- shadow: prep step t+1 (x only; no dependence on h(t))
        if (t + 1 < T) {
            if (l == 0) {
                STAGE_X(t + 1);                       // ungated (static input)
                MEMBAR(); SBAR();
                // publishes AFTER the stage loads -> counted waits exclude them
                if (tid == 192) {
                    st_plain32(iflagV + cid * 32 + w, (unsigned)(t + 1));  // XCD L2
                    st_wt32(mflagV + cid * 32 + w, (unsigned)(t + 1));     // MALL mirror
                }
                if (tid == 128 && t > 0) aaddMALL(cflagS + cid * 32);
                SBAR();
                if (wv == 3)                asm volatile("s_waitcnt vmcnt(2)" ::: "memory");
                else if (wv == 2 && t > 0)  asm volatile("s_waitcnt vmcnt(1)" ::: "memory");
                else                        asm volatile("s_waitcnt vmcnt(0)" ::: "memory");
            } else {
                if (tid == 192) {
                    st_plain32(iflagV + cid * 32 + w, (unsigned)(t + 1));
                    st_wt32(mflagV + cid * 32 + w, (unsigned)(t + 1));
                }
                if (tid == 128 && l == 1 && t > 0) aaddMALL(cflagS + cid * 32);
                CPOLL(t + 1);                         // wave1 gate (producer data)
                RAWBAR();                             // B2b: gate covers ALL waves
                STAGE_X(t + 1);
                asm volatile("s_waitcnt vmcnt(0)" ::: "memory");
            }
            RAWBAR();                                 // B3: x(t+1) staged
            e0 = (f32x4){0,0,0,0}; e1 = (f32x4){0,0,0,0};
            o0 = (f32x4){0,0,0,0}; o1 = (f32x4){0,0,0,0};
            { XH(e0, e1, o0, o1, A00, A01) }
            if (P == 2) {
                e2 = (f32x4){0,0,0,0}; e3 = (f32x4){0,0,0,0};
                o2 = (f32x4){0,0,0,0}; o3 = (f32x4){0,0,0,0};
                XH(e2, e3, o2, o3, A10, A11)
            }
        }
    }

    // ---- epilogue: final publishes (restores stale-reject margin + sums)
    asm volatile("s_waitcnt vmcnt(0)" ::: "memory");
    __builtin_amdgcn_s_barrier();
    if (tid == 192) {
        st_plain32(iflagV + cid * 32 + w, (unsigned)T);     // final iflag = T
        st_wt32(mflagV + cid * 32 + w, (unsigned)T);
    }
    if (tid == 128 && l < 2) {                              // 2 adds -> sum 32*T
        aaddMALL(cflagS + cid * 32);
        aaddMALL(cflagS + cid * 32);
    }
}

extern "C" void kernel_launch(void* const* d_in, const int* in_sizes, int n_in,
                              void* d_out, int out_size, void* d_ws, size_t ws_size,
                              hipStream_t stream)
{
    const float* x = (const float*)d_in[0];
    const float* Wih[3] = {(const float*)d_in[1], (const float*)d_in[5], (const float*)d_in[9]};
    const float* Whh[3] = {(const float*)d_in[2], (const float*)d_in[6], (const float*)d_in[10]};
    const float* bih[3] = {(const float*)d_in[3], (const float*)d_in[7], (const float*)d_in[11]};
    const float* bhh[3] = {(const float*)d_in[4], (const float*)d_in[8], (const float*)d_in[12]};

    char* wp = (char*)d_ws;
    const size_t SZ_A = (size_t)16384 * 512;
    unsigned int* flags = (unsigned int*)wp; wp += 4096;
    unsigned short* Xp  = (unsigned short*)wp; wp += SZ_A * 2;
    unsigned short* Hp0 = (unsigned short*)wp; wp += SZ_A * 2;
    unsigned short* Hp1 = (unsigned short*)wp; wp += SZ_A * 2;
    unsigned short* Hp2 = (unsigned short*)wp; wp += SZ_A * 2;
    unsigned short* Wp[3];
    for (int l = 0; l < 3; ++l) { Wp[l] = (unsigned short*)wp; wp += (size_t)2048 * 1024 * 2; }
    unsigned short* Xq1 = (unsigned short*)wp; wp += SZ_A * 2;
    unsigned short* Xq2 = (unsigned short*)wp; wp += SZ_A * 2;
    const size_t need = (size_t)(wp - (char*)d_ws);
    if (ws_size < need) { Xq1 = Hp0; Xq2 = Hp1; }   // fallback: sc1-only h path

    hipMemsetAsync(flags, 0, 4096, stream);
    k_conv_x<<<dim3(4096), dim3(256), 0, stream>>>(x, Xp);
    for (int l = 0; l < 3; ++l)
        k_conv_w<<<dim3(1024), dim3(256), 0, stream>>>(Wih[l], Whh[l], Wp[l]);

    DP dp;
    dp.Xp = Xp; dp.Hp0 = Hp0; dp.Hp1 = Hp1; dp.Hp2 = Hp2;
    dp.Xq1 = Xq1; dp.Xq2 = Xq2;
    dp.Wp0 = Wp[0]; dp.Wp1 = Wp[1]; dp.Wp2 = Wp[2];
    dp.bi0 = bih[0]; dp.bh0 = bhh[0];
    dp.bi1 = bih[1]; dp.bh1 = bhh[1];
    dp.bi2 = bih[2]; dp.bh2 = bhh[2];
    dp.Out = (float*)d_out; dp.flags = flags;

    k_drnn<<<dim3(256), dim3(256), 0, stream>>>(dp);
}

// Round 16
// 883.008 us; speedup vs baseline: 2.0471x; 1.0580x over previous
//
#include <hip/hip_runtime.h>

typedef __attribute__((ext_vector_type(8))) short bf16x8;
typedef __attribute__((ext_vector_type(4))) float f32x4;

__device__ __forceinline__ unsigned short f2bf(float x) {
    unsigned u = __float_as_uint(x);
    u += 0x7FFFu + ((u >> 16) & 1u);
    return (unsigned short)(u >> 16);
}
__device__ __forceinline__ float sigm(float x) { return 1.0f / (1.0f + __expf(-x)); }
__device__ __forceinline__ float ftanh(float x) {
    float e = __expf(2.f * x);
    return 1.f - 2.f / (e + 1.f);
}

// async global->LDS, 16B/lane, wave-uniform LDS base + lane*16
__device__ __forceinline__ void gld16(const unsigned short* g, unsigned short* l) {
    __builtin_amdgcn_global_load_lds((const __attribute__((address_space(1))) void*)g,
                                     (__attribute__((address_space(3))) void*)l, 16, 0, 0);
}

// ---- flag primitives ----
__device__ __forceinline__ void st_plain32(unsigned* p, unsigned v) {  // -> XCD L2 (write-through)
    asm volatile("global_store_dword %0, %1, off" :: "v"(p), "v"(v) : "memory");
}
__device__ __forceinline__ void st_wt32(unsigned* p, unsigned v) {     // -> MALL
    asm volatile("global_store_dword %0, %1, off sc0 sc1" :: "v"(p), "v"(v) : "memory");
}
__device__ __forceinline__ void aaddMALL(unsigned* p) {
    unsigned one = 1;
    asm volatile("global_atomic_add %0, %1, off sc1" :: "v"(p), "v"(one) : "memory");
}
__device__ __forceinline__ unsigned ld_mall(const unsigned* p) {       // read MALL
    unsigned v;
    asm volatile("global_load_dword %0, %1, off sc0 sc1\n\ts_waitcnt vmcnt(0)"
                 : "=v"(v) : "v"(p) : "memory");
    return v;
}
__device__ __forceinline__ void st_wt16(unsigned short* p, unsigned v) {
    asm volatile("global_store_short %0, %1, off sc0 sc1" :: "v"(p), "v"(v) : "memory");
}

// DPP quad-lane exchanges (1-cycle VALU)
__device__ __forceinline__ float dppx1(float x) {
    return __int_as_float(__builtin_amdgcn_mov_dpp(__float_as_int(x), 0xB1, 0xF, 0xF, true));
}
__device__ __forceinline__ float dppx2(float x) {
    return __int_as_float(__builtin_amdgcn_mov_dpp(__float_as_int(x), 0x4E, 0xF, 0xF, true));
}

// ---------------- packing kernels (round-6-verified) ----------------
__global__ __launch_bounds__(256) void k_conv_x(const float* __restrict__ x,
                                                unsigned short* __restrict__ Xp) {
    int i = blockIdx.x * 256 + threadIdx.x;
    int rb = i >> 10, kc = (i >> 6) & 15, ln = i & 63;
    int row = (rb << 4) + (ln & 15);
    int k   = (kc << 5) + ((ln >> 4) << 3);
    const float* s = x + (size_t)row * 512 + k;
    float4 v0 = *(const float4*)s, v1 = *(const float4*)(s + 4);
    unsigned short o[8] = {f2bf(v0.x), f2bf(v0.y), f2bf(v0.z), f2bf(v0.w),
                           f2bf(v1.x), f2bf(v1.y), f2bf(v1.z), f2bf(v1.w)};
    *(bf16x8*)(Xp + (size_t)i * 8) = *(bf16x8*)o;
}

__global__ __launch_bounds__(256) void k_conv_w(const float* __restrict__ Wih,
                                                const float* __restrict__ Whh,
                                                unsigned short* __restrict__ Wp) {
    int i = blockIdx.x * 256 + threadIdx.x;
    int wrb = i >> 11, kc = (i >> 6) & 31, ln = i & 63;
    int j = (wrb << 4) + (ln & 15);
    int k = (kc << 5) + ((ln >> 4) << 3);
    int srow = (j & 3) * 512 + (j >> 2);              // torch row g*512+hc
    const float* s = (k < 512) ? (Wih + (size_t)srow * 512 + k)
                               : (Whh + (size_t)srow * 512 + (k - 512));
    float4 v0 = *(const float4*)s, v1 = *(const float4*)(s + 4);
    unsigned short o[8] = {f2bf(v0.x), f2bf(v0.y), f2bf(v0.z), f2bf(v0.w),
                           f2bf(v1.x), f2bf(v1.y), f2bf(v1.z), f2bf(v1.w)};
    *(bf16x8*)(Wp + (size_t)i * 8) = *(bf16x8*)o;
}

struct DP {
    const unsigned short* Xp;
    unsigned short *Hp0, *Hp1, *Hp2;
    unsigned short *Xq1, *Xq2;
    const unsigned short *Wp0, *Wp1, *Wp2;
    const float *bi0, *bh0, *bi1, *bh1, *bi2, *bh2;
    float* Out;
    unsigned int* flags;   // [0,256) iflagV, [256,512) mflagV, [512,768) cflagS
};

__device__ __forceinline__ void quadT(f32x4 a, int sq, float& G0, float& G1, float& G2, float& G3) {
    float a0 = a[0], a1 = a[1], a2 = a[2], a3 = a[3];
    float p1 = (sq & 1) ? a0 : a1; float g1_ = dppx1(p1);
    float p2 = (sq & 1) ? a2 : a3; float g2_ = dppx1(p2);
    float m0 = (sq & 1) ? g1_ : a0, m1 = (sq & 1) ? a1 : g1_;
    float m2 = (sq & 1) ? g2_ : a2, m3 = (sq & 1) ? a3 : g2_;
    float q1 = (sq & 2) ? m0 : m2; float h1_ = dppx2(q1);
    float q2 = (sq & 2) ? m1 : m3; float h2_ = dppx2(q2);
    G0 = (sq & 2) ? h1_ : m0; G1 = (sq & 2) ? h2_ : m1;
    G2 = (sq & 2) ? m2 : h1_; G3 = (sq & 2) ? m3 : h2_;
}

#define PIN8(A,B,C,D,E,F,G,H) \
    asm volatile("" : "+v"(A),"+v"(B),"+v"(C),"+v"(D),"+v"(E),"+v"(F),"+v"(G),"+v"(H))
#define SBAR()  __builtin_amdgcn_sched_barrier(0)
#define MEMBAR() asm volatile("" ::: "memory")
#define RAWBAR() do { MEMBAR(); SBAR(); __builtin_amdgcn_s_barrier(); SBAR(); MEMBAR(); } while (0)
#define VMC(n) asm volatile("s_waitcnt vmcnt(" #n ")" ::: "memory")

// Persistent dilated-LSTM, grid 256, XCD-clustered (cid = bid&7, w = bid>>3).
// r16 KEY FIX: vmcnt retires in ISSUE ORDER, so MALL-bound stores (st_wt16
// Xq copies, pubs) must be issued NEWEST in each wave's queue or every
// counted wait eats their ~1000-1500cy ack. New per-step order (l==0):
//   Hd plain stores -> STAGE_X gld16 -> wt16 -> vmcnt(10) [drains Hd only,
//   overlapped with gld16 flight] -> B2 -> pubs(w3) -> w3 vmcnt(5|4) /
//   others vmcnt(2) [wt16+pubs stay flying; retire during XH+poll] -> B3
//   -> XH. Last step issues wt16 in the tail. l==1 same behind the CPOLL
//   gate; l==2 leaves the 4 Out stores flying via vmcnt(4).
// t==0: explicit guard RAWBAR before l==0's first x-overwrite (prologue XH).
// Flag mechanisms = r13/r15 (proven): plain-store iflag publish + gld16
// poll (exact-match (v-t)<=1; t==T-1 via MALL mirror; 1024-iter permanent
// escalation); cflag = MALL sums, one step delayed, totals 32*T.
__global__ __launch_bounds__(256, 1) void k_drnn(DP p) {
    const int tid = threadIdx.x, lane = tid & 63, wv = tid >> 6;
    const int l15 = lane & 15, lhi = lane >> 4, sq = l15 & 3;

    const int b = blockIdx.x;
    const int cid = b & 7, w = b >> 3;
    int l, c, T, P, N;
    if (cid < 2)      { l = 0; c = cid;     T = 256; P = 1; N = 64;  }
    else if (cid < 4) { l = 1; c = cid - 2; T = 128; P = 2; N = 128; }
    else              { l = 2; c = cid - 4; T = 64;  P = 2; N = 256; }

    const unsigned short* Xs = (l == 0) ? p.Xp  : (l == 1 ? p.Xq1 : p.Xq2);
    unsigned short*       Hd = (l == 0) ? p.Hp0 : (l == 1 ? p.Hp1 : p.Hp2);
    unsigned short*       Xw = (l == 0) ? p.Xq1 : (l == 1 ? p.Xq2 : nullptr);
    const unsigned short* Ws = (l == 0) ? p.Wp0 : (l == 1 ? p.Wp1 : p.Wp2);
    const float* bi = (l == 0) ? p.bi0 : (l == 1 ? p.bi1 : p.bi2);
    const float* bh = (l == 0) ? p.bh0 : (l == 1 ? p.bh1 : p.bh2);
    const int R0 = c * (P * 32);
    const int alias = (p.Xq1 == p.Hp0);

    __shared__ unsigned short At[65536];   // 128 KiB
    __shared__ unsigned pollbuf[32];       // flag-line scratch

    const unsigned short* wbase = Ws + ((size_t)(((w << 2) + wv) * 32) << 9) + lane * 8;
#define DECLW(n) bf16x8 w##n = *(const bf16x8*)(wbase + (n << 9));
    DECLW(0) DECLW(1) DECLW(2) DECLW(3) DECLW(4) DECLW(5) DECLW(6) DECLW(7)
    DECLW(8) DECLW(9) DECLW(10) DECLW(11) DECLW(12) DECLW(13) DECLW(14) DECLW(15)
    DECLW(16) DECLW(17) DECLW(18) DECLW(19) DECLW(20) DECLW(21) DECLW(22) DECLW(23)
    DECLW(24) DECLW(25) DECLW(26) DECLW(27) DECLW(28) DECLW(29) DECLW(30) DECLW(31)

    const int hcol = (w << 4) + (wv << 2) + (l15 >> 2);
    const float bs0 = bi[hcol]        + bh[hcol];
    const float bs1 = bi[512 + hcol]  + bh[512 + hcol];
    const float bs2 = bi[1024 + hcol] + bh[1024 + hcol];
    const float bs3 = bi[1536 + hcol] + bh[1536 + hcol];

    const int kch = hcol >> 5;
    const int lane16 = (((hcol & 31) >> 3) << 4) + ((lhi << 2) + sq);
    const int st_lt = lane16 * 8 + (hcol & 7);

    float cst0 = 0.f, cst1 = 0.f, cst2 = 0.f, cst3 = 0.f;
    unsigned int* iflagV = p.flags;
    unsigned int* mflagV = p.flags + 256;
    unsigned int* cflagS = p.flags + 512;
    int fastok = 1;

#define KPX(na, nb, E0, E1, O0, O1, A0, A1) { \
    bf16x8 xa = *(const bf16x8*)((A0) + ((na) << 9)); \
    bf16x8 xb = *(const bf16x8*)((A1) + ((na) << 9)); \
    bf16x8 ya = *(const bf16x8*)((A0) + ((nb) << 9)); \
    bf16x8 yb = *(const bf16x8*)((A1) + ((nb) << 9)); \
    E0 = __builtin_amdgcn_mfma_f32_16x16x32_bf16(xa, w##na, E0, 0, 0, 0); \
    E1 = __builtin_amdgcn_mfma_f32_16x16x32_bf16(xb, w##na, E1, 0, 0, 0); \
    O0 = __builtin_amdgcn_mfma_f32_16x16x32_bf16(ya, w##nb, O0, 0, 0, 0); \
    O1 = __builtin_amdgcn_mfma_f32_16x16x32_bf16(yb, w##nb, O1, 0, 0, 0); }

#define XH(E0, E1, O0, O1, A0, A1) \
    KPX(0,1,E0,E1,O0,O1,A0,A1) KPX(2,3,E0,E1,O0,O1,A0,A1) \
    KPX(4,5,E0,E1,O0,O1,A0,A1) KPX(6,7,E0,E1,O0,O1,A0,A1) \
    KPX(8,9,E0,E1,O0,O1,A0,A1) KPX(10,11,E0,E1,O0,O1,A0,A1) \
    KPX(12,13,E0,E1,O0,O1,A0,A1) KPX(14,15,E0,E1,O0,O1,A0,A1)
#define HH(E0, E1, O0, O1, A0, A1) \
    KPX(16,17,E0,E1,O0,O1,A0,A1) KPX(18,19,E0,E1,O0,O1,A0,A1) \
    KPX(20,21,E0,E1,O0,O1,A0,A1) KPX(22,23,E0,E1,O0,O1,A0,A1) \
    KPX(24,25,E0,E1,O0,O1,A0,A1) KPX(26,27,E0,E1,O0,O1,A0,A1) \
    KPX(28,29,E0,E1,O0,O1,A0,A1) KPX(30,31,E0,E1,O0,O1,A0,A1)

#define PWC(RV, CSTV, HV) { \
    float G0, G1, G2, G3; quadT(RV, sq, G0, G1, G2, G3); \
    float cn = sigm(G1 + bs1) * CSTV + sigm(G0 + bs0) * ftanh(G2 + bs2); \
    HV = sigm(G3 + bs3) * ftanh(cn); CSTV = cn; }

#define STAGE_X(TT) { \
    const int RxN = ((TT) * N + R0) >> 4; \
    for (int i = 0; i < P * 8; ++i) { \
        int q = wv * (P * 8) + i, rb = q >> 4, kc = q & 15; \
        gld16(Xs + ((size_t)((RxN + rb) * 16 + kc) << 9) + lane * 8, \
              &At[(rb * 32 + kc) << 9]); } }
#define STAGE_H(TT) { \
    const int RhN = ((TT) * N + R0) >> 4; \
    for (int i = 0; i < P * 8; ++i) { \
        int q = wv * (P * 8) + i, rb = q >> 4, kc = q & 15; \
        gld16(Hd + ((size_t)((RhN + rb) * 16 + kc) << 9) + lane * 8, \
              &At[(rb * 32 + 16 + kc) << 9]); } }

#define CPOLL(TT) { \
    if (l == 1 && wv == 1 && lane < 2) { \
        const unsigned* cp = cflagS + lane * 32; \
        const unsigned need = 32u * (unsigned)(2 * (TT) + c + 1); \
        int n = 0; \
        while (!__all(ld_mall(cp) >= need)) { if (++n > (1 << 22)) break; } \
    } \
    if (l == 2 && wv == 1 && lane == 0) { \
        const unsigned* cp = cflagS + (2 + (c & 1)) * 32; \
        const unsigned need = 32u * (unsigned)(2 * (TT) + (c >> 1) + 1); \
        int n = 0; \
        while (ld_mall(cp) < need) { if (++n > (1 << 22)) break; } \
    } }

    f32x4 e0 = {0,0,0,0}, e1 = {0,0,0,0}, o0 = {0,0,0,0}, o1 = {0,0,0,0};
    f32x4 e2 = {0,0,0,0}, e3 = {0,0,0,0}, o2 = {0,0,0,0}, o3 = {0,0,0,0};
    const unsigned short* A00 = At + lane * 8;
    const unsigned short* A01 = A00 + (32 << 9);
    const unsigned short* A10 = A00 + (64 << 9);
    const unsigned short* A11 = A00 + (96 << 9);

    // ---------- prologue: x(0) staged + x-half partials ----------
    if (l > 0) CPOLL(0);
    RAWBAR();
    STAGE_X(0);
    VMC(0);
    RAWBAR();
    { XH(e0, e1, o0, o1, A00, A01) }
    if (P == 2) { XH(e2, e3, o2, o3, A10, A11) }

    for (int t = 0; t < T; ++t) {
        PIN8(w0,w1,w2,w3,w4,w5,w6,w7);
        PIN8(w8,w9,w10,w11,w12,w13,w14,w15);
        PIN8(w16,w17,w18,w19,w20,w21,w22,w23);
        PIN8(w24,w25,w26,w27,w28,w29,w30,w31);

        const int RxB = (t * N + R0) >> 4;

        if (t > 0) {
            if (wv == 0) {
                const unsigned need = (unsigned)t;
                const unsigned* mp = mflagV + cid * 32 + (lane & 31);
                if (t == T - 1 || !fastok) {         // authoritative MALL gate
                    int n = 0;
                    while (!__all(ld_mall(mp) >= need)) { if (++n > (1 << 22)) break; }
                } else {
                    const unsigned short* gip = (const unsigned short*)(iflagV + cid * 32);
                    volatile unsigned* pb = pollbuf;
                    int n = 0;
                    for (;;) {
                        if (lane < 8) gld16(gip + lane * 8, (unsigned short*)pollbuf);
                        VMC(0);
                        SBAR();
                        unsigned v = pb[lane & 31];
                        if (__all((v - need) <= 1u)) break;
                        if (++n > 1024) {
                            fastok = 0;
                            int m = 0;
                            while (!__all(ld_mall(mp) >= need)) { if (++m > (1 << 22)) break; }
                            break;
                        }
                    }
                }
            }
            RAWBAR();                                 // B0: h(t-1) ready
            STAGE_H(t - 1);
            VMC(0);
            RAWBAR();                                 // B1: h staged
            { HH(e0, e1, o0, o1, A00, A01) }
            if (P == 2) { HH(e2, e3, o2, o3, A10, A11) }
        }

        // ---- pointwise
        float hv0, hv1, hv2 = 0.f, hv3 = 0.f;
        { f32x4 r0 = e0 + o0, r1 = e1 + o1;
          PWC(r0, cst0, hv0) PWC(r1, cst1, hv1) }
        if (P == 2) {
          f32x4 r2 = e2 + o2, r3 = e3 + o3;
          PWC(r2, cst2, hv2) PWC(r3, cst3, hv3) }

        const unsigned short hb0 = f2bf(hv0), hb1 = f2bf(hv1);
        const unsigned short hb2 = f2bf(hv2), hb3 = f2bf(hv3);
        const size_t i0 = ((size_t)((RxB + 0) * 16 + kch) << 9) + st_lt;
        const size_t i1 = ((size_t)((RxB + 1) * 16 + kch) << 9) + st_lt;
        const size_t i2 = ((size_t)((RxB + 2) * 16 + kch) << 9) + st_lt;
        const size_t i3 = ((size_t)((RxB + 3) * 16 + kch) << 9) + st_lt;

        // ---- release stores (plain; MALL wt16 deferred to the shadow)
        if (!alias || l == 2) {
            Hd[i0] = hb0; Hd[i1] = hb1;
            if (P == 2) { Hd[i2] = hb2; Hd[i3] = hb3; }
        }
        if (alias && l < 2) {                        // fallback: wt IS the h store
            st_wt16(Xw + i0, hb0); st_wt16(Xw + i1, hb1);
            if (P == 2) { st_wt16(Xw + i2, hb2); st_wt16(Xw + i3, hb3); }
        }
        if (l == 2) {
            p.Out[((size_t)(((RxB + 0) << 4) + (lhi << 2) + sq)) * 512 + hcol] = hv0;
            p.Out[((size_t)(((RxB + 1) << 4) + (lhi << 2) + sq)) * 512 + hcol] = hv1;
            p.Out[((size_t)(((RxB + 2) << 4) + (lhi << 2) + sq)) * 512 + hcol] = hv2;
            p.Out[((size_t)(((RxB + 3) << 4) + (lhi << 2) + sq)) * 512 + hcol] = hv3;
        }
        MEMBAR(); SBAR();

        if (t + 1 < T) {
            if (l == 0) {
                if (t == 0) RAWBAR();                 // guard: prologue-XH vs x overwrite
                STAGE_X(t + 1);                       // 8 gld16
                if (!alias) { st_wt16(Xw + i0, hb0); st_wt16(Xw + i1, hb1); }
                MEMBAR(); SBAR();
                if (!alias) VMC(10);                  // drain 2 Hd; 8g+2w fly
                else        VMC(8);                   // drain 2 wt16 (h data); 8g fly
                RAWBAR();                             // B2
                if (tid == 192) {
                    st_plain32(iflagV + cid * 32 + w, (unsigned)(t + 1));
                    st_wt32(mflagV + cid * 32 + w, (unsigned)(t + 1));
                    if (t > 0) aaddMALL(cflagS + cid * 32);
                }
                MEMBAR(); SBAR();
                if (!alias) {
                    if (wv == 3) { if (t > 0) VMC(5); else VMC(4); } else VMC(2);
                } else {
                    if (wv == 3) { if (t > 0) VMC(3); else VMC(2); } else VMC(0);
                }
            } else {
                CPOLL(t + 1);                         // wave1 gate (producer data)
                if (l == 2) VMC(4); else VMC(0);      // drain Hd (l2: leave Out)
                RAWBAR();                             // B2 (gate + h drained)
                STAGE_X(t + 1);                       // 16 gld16
                if (l == 1 && !alias) {
                    st_wt16(Xw + i0, hb0); st_wt16(Xw + i1, hb1);
                    st_wt16(Xw + i2, hb2); st_wt16(Xw + i3, hb3);
                }
                MEMBAR(); SBAR();
                if (tid == 192) {
                    st_plain32(iflagV + cid * 32 + w, (unsigned)(t + 1));
                    st_wt32(mflagV + cid * 32 + w, (unsigned)(t + 1));
                    if (l == 1 && t > 0) aaddMALL(cflagS + cid * 32);
                }
                MEMBAR(); SBAR();
                if (l == 1) {
                    if (!alias) { if (wv == 3) { if (t > 0) VMC(7); else VMC(6); } else VMC(4); }
                    else        { if (wv == 3) { if (t > 0) VMC(3); else VMC(2); } else VMC(0); }
                } else {
                    if (wv == 3) VMC(2); else VMC(0);
                }
            }
            RAWBAR();                                 // B3: x(t+1) staged
            e0 = (f32x4){0,0,0,0}; e1 = (f32x4){0,0,0,0};
            o0 = (f32x4){0,0,0,0}; o1 = (f32x4){0,0,0,0};
            { XH(e0, e1, o0, o1, A00, A01) }
            if (P == 2) {
                e2 = (f32x4){0,0,0,0}; e3 = (f32x4){0,0,0,0};
                o2 = (f32x4){0,0,0,0}; o3 = (f32x4){0,0,0,0};
                XH(e2, e3, o2, o3, A10, A11)
            }
        } else {
            // final-step tail: last Xq copy (shadow skipped)
            if (!alias && l == 0) { st_wt16(Xw + i0, hb0); st_wt16(Xw + i1, hb1); }
            if (!alias && l == 1) { st_wt16(Xw + i0, hb0); st_wt16(Xw + i1, hb1);
                                    st_wt16(Xw + i2, hb2); st_wt16(Xw + i3, hb3); }
            MEMBAR(); SBAR();
            VMC(0);
            RAWBAR();
        }
    }

    // ---- epilogue: final publishes (stale-reject margin + exact sums 32*T)
    VMC(0);
    __builtin_amdgcn_s_barrier();
    if (tid == 192) {
        st_plain32(iflagV + cid * 32 + w, (unsigned)T);
        st_wt32(mflagV + cid * 32 + w, (unsigned)T);
        if (l < 2) { aaddMALL(cflagS + cid * 32); aaddMALL(cflagS + cid * 32); }
    }
}

extern "C" void kernel_launch(void* const* d_in, const int* in_sizes, int n_in,
                              void* d_out, int out_size, void* d_ws, size_t ws_size,
                              hipStream_t stream)
{
    const float* x = (const float*)d_in[0];
    const float* Wih[3] = {(const float*)d_in[1], (const float*)d_in[5], (const float*)d_in[9]};
    const float* Whh[3] = {(const float*)d_in[2], (const float*)d_in[6], (const float*)d_in[10]};
    const float* bih[3] = {(const float*)d_in[3], (const float*)d_in[7], (const float*)d_in[11]};
    const float* bhh[3] = {(const float*)d_in[4], (const float*)d_in[8], (const float*)d_in[12]};

    char* wp = (char*)d_ws;
    const size_t SZ_A = (size_t)16384 * 512;
    unsigned int* flags = (unsigned int*)wp; wp += 4096;
    unsigned short* Xp  = (unsigned short*)wp; wp += SZ_A * 2;
    unsigned short* Hp0 = (unsigned short*)wp; wp += SZ_A * 2;
    unsigned short* Hp1 = (unsigned short*)wp; wp += SZ_A * 2;
    unsigned short* Hp2 = (unsigned short*)wp; wp += SZ_A * 2;
    unsigned short* Wp[3];
    for (int l = 0; l < 3; ++l) { Wp[l] = (unsigned short*)wp; wp += (size_t)2048 * 1024 * 2; }
    unsigned short* Xq1 = (unsigned short*)wp; wp += SZ_A * 2;
    unsigned short* Xq2 = (unsigned short*)wp; wp += SZ_A * 2;
    const size_t need = (size_t)(wp - (char*)d_ws);
    if (ws_size < need) { Xq1 = Hp0; Xq2 = Hp1; }   // fallback: sc1-only h path

    hipMemsetAsync(flags, 0, 4096, stream);
    k_conv_x<<<dim3(4096), dim3(256), 0, stream>>>(x, Xp);
    for (int l = 0; l < 3; ++l)
        k_conv_w<<<dim3(1024), dim3(256), 0, stream>>>(Wih[l], Whh[l], Wp[l]);

    DP dp;
    dp.Xp = Xp; dp.Hp0 = Hp0; dp.Hp1 = Hp1; dp.Hp2 = Hp2;
    dp.Xq1 = Xq1; dp.Xq2 = Xq2;
    dp.Wp0 = Wp[0]; dp.Wp1 = Wp[1]; dp.Wp2 = Wp[2];
    dp.bi0 = bih[0]; dp.bh0 = bhh[0];
    dp.bi1 = bih[1]; dp.bh1 = bhh[1];
    dp.bi2 = bih[2]; dp.bh2 = bhh[2];
    dp.Out = (float*)d_out; dp.flags = flags;

    k_drnn<<<dim3(256), dim3(256), 0, stream>>>(dp);
}